// Round 6
// baseline (4110.335 us; speedup 1.0000x reference)
//
#include <hip/hip_runtime.h>

#define B_    16
#define NTOK  256
#define D_    512
#define HEADS 16
#define DH    32
#define DEPTH 12
#define KCODE 2048
#define M_    (B_*NTOK)   // 4096 token rows

typedef __attribute__((ext_vector_type(8))) short short8;     // 8 bf16 (4 VGPRs)
typedef __attribute__((ext_vector_type(4))) float float4v;
typedef __attribute__((ext_vector_type(4))) unsigned int uint4v;
typedef __attribute__((ext_vector_type(2))) unsigned int uint2v;
typedef unsigned short ushort;

__device__ __forceinline__ ushort f2b(float f){   // fp32 -> bf16 RNE
  union { float f; unsigned u; } v; v.f = f;
  unsigned r = v.u + 0x7FFFu + ((v.u >> 16) & 1u);
  return (ushort)(r >> 16);
}
__device__ __forceinline__ float b2f(ushort h){
  union { unsigned u; float f; } v; v.u = ((unsigned)h) << 16; return v.f;
}
__device__ __forceinline__ float bits2f(unsigned u){
  union { unsigned u; float f; } v; v.u = u; return v.f;
}

// ---------------- prep kernels ----------------

__global__ void k_tok_init(const float* __restrict__ x, const float* __restrict__ pos,
                           float* __restrict__ tok){
  int i = blockIdx.x*256 + threadIdx.x;
  if (i >= B_*NTOK*D_) return;
  int d = i % D_; int r = i / D_; int t = r % NTOK; int b = r / NTOK;
  tok[i] = x[(b*D_ + d)*NTOK + t] + pos[t*D_ + d];
}

__global__ void k_split(const float* __restrict__ src, ushort* __restrict__ oh,
                        ushort* __restrict__ ol, int n){
  int i = blockIdx.x*256 + threadIdx.x;
  if (i >= n) return;
  float v = src[i];
  ushort h = f2b(v);
  oh[i] = h; ol[i] = f2b(v - b2f(h));
}

// split + transpose: src [L][K][N] f32 -> dst hi/lo [L][N][K] bf16
__global__ void k_split_t(const float* __restrict__ src, ushort* __restrict__ oh,
                          ushort* __restrict__ ol, int L, int K, int N){
  int i = blockIdx.x*256 + threadIdx.x;
  if (i >= L*K*N) return;
  int KN = K*N;
  int l = i / KN; int r = i - l*KN;
  int k = r / N;  int n = r - k*N;
  float v = src[i];
  ushort h = f2b(v);
  size_t o = (size_t)l*KN + (size_t)n*K + k;
  oh[o] = h; ol[o] = f2b(v - b2f(h));
}

// conv weights: [Cout][Cin][3][3] f32 -> W9 [9tap][Cout][Cin] bf16
__global__ void k_w9(const float* __restrict__ w, ushort* __restrict__ W9,
                     int Cin, int Cout){
  int i = blockIdx.x*256 + threadIdx.x;
  if (i >= Cout*Cin*9) return;
  int co = i / (Cin*9); int r = i - co*(Cin*9);
  int ci = r / 9; int tap = r - ci*9;
  W9[((size_t)tap*Cout + co)*Cin + ci] = f2b(w[i]);
}

// upconv weights: [Cin][Cout][2][2] f32 -> Wt4 [tap][Cout][Cin] bf16
__global__ void k_upw(const float* __restrict__ w, ushort* __restrict__ Wt4,
                      int Cin, int Cout){
  int i = blockIdx.x*256 + threadIdx.x;
  if (i >= Cin*Cout*4) return;
  int ci = i / (Cout*4); int r = i - ci*(Cout*4);
  int co = r >> 2; int tap = r & 3;
  Wt4[((size_t)tap*Cout + co)*Cin + ci] = f2b(w[i]);
}

// LayerNorm fused with bf16 hi/lo split
__global__ void k_ln_split(const float* __restrict__ in, ushort* __restrict__ oh,
                           ushort* __restrict__ ol, const float* __restrict__ g,
                           const float* __restrict__ bta){
  int row = blockIdx.x; int t = threadIdx.x;
  const float* xr = in + (size_t)row*D_;
  float x0 = xr[t], x1 = xr[t+256];
  __shared__ float r1[256], r2[256];
  r1[t] = x0+x1; r2[t] = x0*x0 + x1*x1;
  __syncthreads();
  for (int off=128; off>0; off>>=1){
    if (t<off){ r1[t]+=r1[t+off]; r2[t]+=r2[t+off]; }
    __syncthreads();
  }
  float mean = r1[0] * (1.f/D_);
  float var  = r2[0] * (1.f/D_) - mean*mean;
  float inv  = rsqrtf(var + 1e-5f);
  float y0 = (x0-mean)*inv*g[t]     + bta[t];
  float y1 = (x1-mean)*inv*g[t+256] + bta[t+256];
  size_t o = (size_t)row*D_;
  ushort h0 = f2b(y0), h1 = f2b(y1);
  oh[o+t] = h0;     ol[o+t]     = f2b(y0 - b2f(h0));
  oh[o+t+256] = h1; ol[o+t+256] = f2b(y1 - b2f(h1));
}

// ---------------- split-bf16 MFMA GEMM (3-term, fp32-accurate) ----------------
__global__ __launch_bounds__(256) void k_gemm_split(
    const ushort* __restrict__ Ah, const ushort* __restrict__ Al,
    const ushort* __restrict__ Bh, const ushort* __restrict__ Bl,
    float* __restrict__ C, const float* __restrict__ bias,
    const float* __restrict__ resid, int M, int N, int K){
  __shared__ ushort Ash[64][40], Asl[64][40], Bsh[64][40], Bsl[64][40];
  const int tid = threadIdx.x;
  const int m_base = blockIdx.x*64, n_base = blockIdx.y*64;
  const int lane = tid & 63, wv = tid >> 6;
  const int quad = lane >> 4, r16 = lane & 15;
  const int m_off = (wv & 1)*32, n_off = (wv >> 1)*32;
  const int srow = tid & 63, skq = tid >> 6;
  const size_t arow = (size_t)(m_base + srow)*K + skq*8;
  const size_t brow = (size_t)(n_base + srow)*K + skq*8;
  float4v acc00={}, acc01={}, acc10={}, acc11={};
  for (int k0 = 0; k0 < K; k0 += 32){
    *(uint4v*)&Ash[srow][skq*8] = *(const uint4v*)(Ah + arow + k0);
    *(uint4v*)&Asl[srow][skq*8] = *(const uint4v*)(Al + arow + k0);
    *(uint4v*)&Bsh[srow][skq*8] = *(const uint4v*)(Bh + brow + k0);
    *(uint4v*)&Bsl[srow][skq*8] = *(const uint4v*)(Bl + brow + k0);
    __syncthreads();
    short8 afh0 = *(const short8*)&Ash[m_off      + r16][quad*8];
    short8 afh1 = *(const short8*)&Ash[m_off + 16 + r16][quad*8];
    short8 afl0 = *(const short8*)&Asl[m_off      + r16][quad*8];
    short8 afl1 = *(const short8*)&Asl[m_off + 16 + r16][quad*8];
    short8 bfh0 = *(const short8*)&Bsh[n_off      + r16][quad*8];
    short8 bfh1 = *(const short8*)&Bsh[n_off + 16 + r16][quad*8];
    short8 bfl0 = *(const short8*)&Bsl[n_off      + r16][quad*8];
    short8 bfl1 = *(const short8*)&Bsl[n_off + 16 + r16][quad*8];
    acc00 = __builtin_amdgcn_mfma_f32_16x16x32_bf16(bfh0, afh0, acc00, 0,0,0);
    acc00 = __builtin_amdgcn_mfma_f32_16x16x32_bf16(bfh0, afl0, acc00, 0,0,0);
    acc00 = __builtin_amdgcn_mfma_f32_16x16x32_bf16(bfl0, afh0, acc00, 0,0,0);
    acc01 = __builtin_amdgcn_mfma_f32_16x16x32_bf16(bfh1, afh0, acc01, 0,0,0);
    acc01 = __builtin_amdgcn_mfma_f32_16x16x32_bf16(bfh1, afl0, acc01, 0,0,0);
    acc01 = __builtin_amdgcn_mfma_f32_16x16x32_bf16(bfl1, afh0, acc01, 0,0,0);
    acc10 = __builtin_amdgcn_mfma_f32_16x16x32_bf16(bfh0, afh1, acc10, 0,0,0);
    acc10 = __builtin_amdgcn_mfma_f32_16x16x32_bf16(bfh0, afl1, acc10, 0,0,0);
    acc10 = __builtin_amdgcn_mfma_f32_16x16x32_bf16(bfl0, afh1, acc10, 0,0,0);
    acc11 = __builtin_amdgcn_mfma_f32_16x16x32_bf16(bfh1, afh1, acc11, 0,0,0);
    acc11 = __builtin_amdgcn_mfma_f32_16x16x32_bf16(bfh1, afl1, acc11, 0,0,0);
    acc11 = __builtin_amdgcn_mfma_f32_16x16x32_bf16(bfl1, afh1, acc11, 0,0,0);
    __syncthreads();
  }
  int m0 = m_base + m_off + r16;
  int n0 = n_base + n_off + quad*4;
  float4v bv0 = {}, bv1 = {};
  if (bias){ bv0 = *(const float4v*)(bias + n0); bv1 = *(const float4v*)(bias + n0 + 16); }
  float4v v00 = acc00 + bv0, v01 = acc01 + bv1, v10 = acc10 + bv0, v11 = acc11 + bv1;
  if (resid){
    v00 += *(const float4v*)(resid + (size_t)m0*N + n0);
    v01 += *(const float4v*)(resid + (size_t)m0*N + n0 + 16);
    v10 += *(const float4v*)(resid + (size_t)(m0+16)*N + n0);
    v11 += *(const float4v*)(resid + (size_t)(m0+16)*N + n0 + 16);
  }
  *(float4v*)(C + (size_t)m0*N + n0)          = v00;
  *(float4v*)(C + (size_t)m0*N + n0 + 16)     = v01;
  *(float4v*)(C + (size_t)(m0+16)*N + n0)     = v10;
  *(float4v*)(C + (size_t)(m0+16)*N + n0 + 16)= v11;
}

// ---------------- attention: one block per (b,h), K/V in LDS ----------------
__global__ __launch_bounds__(256) void k_attn2(const float* __restrict__ qkv,
                                               ushort* __restrict__ oh,
                                               ushort* __restrict__ ol){
  __shared__ float4v ks[NTOK*8];
  __shared__ float4v vs[NTOK*8];
  const int h = blockIdx.x, b = blockIdx.y, t = threadIdx.x;
  const float* base = qkv + (size_t)b*NTOK*1536;
  const int koff = 512 + h*DH, voff = 1024 + h*DH;
  for (int i = t; i < NTOK*8; i += 256){
    int j = i >> 3, d4 = i & 7;
    ks[i] = *(const float4v*)(base + (size_t)j*1536 + koff + d4*4);
    vs[i] = *(const float4v*)(base + (size_t)j*1536 + voff + d4*4);
  }
  float4v q8[8];
  const float* qrow = base + (size_t)t*1536 + h*DH;
  #pragma unroll
  for (int d4 = 0; d4 < 8; ++d4) q8[d4] = *(const float4v*)(qrow + d4*4);
  __syncthreads();
  float4v o8[8];
  #pragma unroll
  for (int d4 = 0; d4 < 8; ++d4) o8[d4] = float4v{0.f,0.f,0.f,0.f};
  float l = 0.f;
  for (int j = 0; j < NTOK; ++j){
    float s = 0.f;
    #pragma unroll
    for (int d4 = 0; d4 < 8; ++d4){
      float4v kk = ks[j*8 + d4];
      s += q8[d4].x*kk.x + q8[d4].y*kk.y + q8[d4].z*kk.z + q8[d4].w*kk.w;
    }
    float e = __expf(s * 0.17677669529663689f);
    l += e;
    #pragma unroll
    for (int d4 = 0; d4 < 8; ++d4){
      float4v vv = vs[j*8 + d4];
      o8[d4].x += e*vv.x; o8[d4].y += e*vv.y; o8[d4].z += e*vv.z; o8[d4].w += e*vv.w;
    }
  }
  float inv = 1.f / l;
  size_t ob = (size_t)(b*NTOK + t)*D_ + h*DH;
  #pragma unroll
  for (int d4 = 0; d4 < 8; ++d4){
    float vals[4] = {o8[d4].x*inv, o8[d4].y*inv, o8[d4].z*inv, o8[d4].w*inv};
    #pragma unroll
    for (int r = 0; r < 4; ++r){
      ushort hh = f2b(vals[r]);
      oh[ob + d4*4 + r] = hh;
      ol[ob + d4*4 + r] = f2b(vals[r] - b2f(hh));
    }
  }
}

// ---------------- VQ ----------------
__global__ void k_cnorm(const float* __restrict__ cb, float* __restrict__ cnorm){
  int k = blockIdx.x, t = threadIdx.x;
  float v1 = cb[(size_t)k*D_ + t];
  float v2 = cb[(size_t)k*D_ + t + 256];
  __shared__ float r[256];
  r[t] = v1*v1 + v2*v2;
  __syncthreads();
  for (int off=128; off>0; off>>=1){
    if (t<off) r[t]+=r[t+off];
    __syncthreads();
  }
  if (t==0) cnorm[k] = r[0];
}

__global__ void k_argmin(const float* __restrict__ d2, const float* __restrict__ cnorm,
                         int* __restrict__ idx){
  int m = blockIdx.x, t = threadIdx.x;
  float best = 3.4e38f; int bk = 0;
  for (int k = t; k < KCODE; k += 256){
    float s = cnorm[k] - 2.f*d2[(size_t)m*KCODE + k];
    if (s < best){ best = s; bk = k; }
  }
  __shared__ float bs[256]; __shared__ int bi[256];
  bs[t]=best; bi[t]=bk;
  __syncthreads();
  for (int off=128; off>0; off>>=1){
    if (t<off){
      if (bs[t+off] < bs[t] || (bs[t+off]==bs[t] && bi[t+off]<bi[t])){
        bs[t]=bs[t+off]; bi[t]=bi[t+off];
      }
    }
    __syncthreads();
  }
  if (t==0) idx[m] = bi[0];
}

// y0 NHWC bf16: y0[b][t][d] = codebook[idx[b,t]][d]
__global__ void k_gather_nhwc(const float* __restrict__ cb, const int* __restrict__ idx,
                              ushort* __restrict__ y0){
  int i = blockIdx.x*256 + threadIdx.x;
  if (i >= B_*NTOK*D_) return;
  int d = i % D_; int r = i / D_; int t = r % NTOK; int b = r / NTOK;
  y0[i] = f2b(cb[(size_t)idx[b*NTOK + t]*D_ + d]);
}

// ---------------- decoder (NHWC bf16) ----------------

// 3x3 conv pad1 implicit GEMM, per-tap K loop. X [B][HW][Cin] bf16,
// W9 [9][Cout][Cin] bf16, Y [B][HW][Cout] fp32. grid (HW/64, Cout/64, B_).
__global__ __launch_bounds__(256) void k_conv_nhwc(
    const ushort* __restrict__ X, const ushort* __restrict__ W9,
    float* __restrict__ Y, int Cin, int Cout, int H, int W){
  __shared__ ushort Xs[64][40], Ws[64][40];
  const int HW = H*W;
  const int tid = threadIdx.x;
  const int b = blockIdx.z;
  const int m_base = blockIdx.x*64;   // pixel tile
  const int n_base = blockIdx.y*64;   // cout tile
  const int lane = tid & 63, wv = tid >> 6;
  const int quad = lane >> 4, r16 = lane & 15;
  const int m_off = (wv & 1)*32, n_off = (wv >> 1)*32;
  const int srow = tid & 63, skq = tid >> 6;
  const int p = m_base + srow;
  const int pr = p / W, pc = p - pr*W;
  const ushort* Xb = X + (size_t)b*HW*Cin;
  const uint4v zz = {};
  float4v a00={}, a01={}, a10={}, a11={};
  for (int tap = 0; tap < 9; ++tap){
    int kh = tap/3, kw = tap - kh*3;
    int ih = pr + kh - 1, iw = pc + kw - 1;
    bool ok = (ih >= 0 && ih < H && iw >= 0 && iw < W);
    const ushort* xrow = Xb + (size_t)(ih*W + iw)*Cin + skq*8;
    const ushort* wrow = W9 + ((size_t)tap*Cout + n_base + srow)*Cin + skq*8;
    for (int k0 = 0; k0 < Cin; k0 += 32){
      uint4v xv = ok ? *(const uint4v*)(xrow + k0) : zz;
      *(uint4v*)&Xs[srow][skq*8] = xv;
      *(uint4v*)&Ws[srow][skq*8] = *(const uint4v*)(wrow + k0);
      __syncthreads();
      short8 xf0 = *(const short8*)&Xs[m_off      + r16][quad*8];
      short8 xf1 = *(const short8*)&Xs[m_off + 16 + r16][quad*8];
      short8 wf0 = *(const short8*)&Ws[n_off      + r16][quad*8];
      short8 wf1 = *(const short8*)&Ws[n_off + 16 + r16][quad*8];
      // mfma(W,X): D regs (quad*4+r) -> co, D col (lane&15) -> pixel
      a00 = __builtin_amdgcn_mfma_f32_16x16x32_bf16(wf0, xf0, a00, 0,0,0);
      a01 = __builtin_amdgcn_mfma_f32_16x16x32_bf16(wf0, xf1, a01, 0,0,0);
      a10 = __builtin_amdgcn_mfma_f32_16x16x32_bf16(wf1, xf0, a10, 0,0,0);
      a11 = __builtin_amdgcn_mfma_f32_16x16x32_bf16(wf1, xf1, a11, 0,0,0);
      __syncthreads();
    }
  }
  float* Yb = Y + (size_t)b*HW*Cout;
  int px0 = m_base + m_off + r16, px1 = px0 + 16;
  int co0 = n_base + n_off + quad*4, co1 = co0 + 16;
  *(float4v*)(Yb + (size_t)px0*Cout + co0) = a00;
  *(float4v*)(Yb + (size_t)px1*Cout + co0) = a01;
  *(float4v*)(Yb + (size_t)px0*Cout + co1) = a10;
  *(float4v*)(Yb + (size_t)px1*Cout + co1) = a11;
}

// ConvTranspose2d k=2 s=2: X staged once per K-chunk, 4 weight taps share it.
// X [B][HWi][Cin] bf16, Wt4 [4][Cout][Cin] bf16, CC [B][HWo][Ctot] bf16 (ch 0..Cout).
__global__ __launch_bounds__(256) void k_upconv_nhwc(
    const ushort* __restrict__ X, const ushort* __restrict__ Wt4,
    const float* __restrict__ bias, ushort* __restrict__ CC,
    int Cin, int Cout, int Hi, int Wi, int Ctot){
  __shared__ ushort Xs[64][40], Ws[4][64][40];
  const int HWi = Hi*Wi;
  const int tid = threadIdx.x;
  const int b = blockIdx.z;
  const int m_base = blockIdx.x*64;   // input-pixel tile
  const int n_base = blockIdx.y*64;   // cout tile
  const int lane = tid & 63, wv = tid >> 6;
  const int quad = lane >> 4, r16 = lane & 15;
  const int m_off = (wv & 1)*32, n_off = (wv >> 1)*32;
  const int srow = tid & 63, skq = tid >> 6;
  const ushort* xrow = X + ((size_t)b*HWi + m_base + srow)*Cin + skq*8;
  const ushort* w0 = Wt4 + ((size_t)0*Cout + n_base + srow)*Cin + skq*8;
  const ushort* w1 = Wt4 + ((size_t)1*Cout + n_base + srow)*Cin + skq*8;
  const ushort* w2 = Wt4 + ((size_t)2*Cout + n_base + srow)*Cin + skq*8;
  const ushort* w3 = Wt4 + ((size_t)3*Cout + n_base + srow)*Cin + skq*8;
  float4v acc[4][4];
  #pragma unroll
  for (int t = 0; t < 4; ++t)
    #pragma unroll
    for (int q = 0; q < 4; ++q) acc[t][q] = float4v{0.f,0.f,0.f,0.f};
  for (int k0 = 0; k0 < Cin; k0 += 32){
    *(uint4v*)&Xs[srow][skq*8]    = *(const uint4v*)(xrow + k0);
    *(uint4v*)&Ws[0][srow][skq*8] = *(const uint4v*)(w0 + k0);
    *(uint4v*)&Ws[1][srow][skq*8] = *(const uint4v*)(w1 + k0);
    *(uint4v*)&Ws[2][srow][skq*8] = *(const uint4v*)(w2 + k0);
    *(uint4v*)&Ws[3][srow][skq*8] = *(const uint4v*)(w3 + k0);
    __syncthreads();
    short8 xf0 = *(const short8*)&Xs[m_off      + r16][quad*8];
    short8 xf1 = *(const short8*)&Xs[m_off + 16 + r16][quad*8];
    #pragma unroll
    for (int t = 0; t < 4; ++t){
      short8 wf0 = *(const short8*)&Ws[t][n_off      + r16][quad*8];
      short8 wf1 = *(const short8*)&Ws[t][n_off + 16 + r16][quad*8];
      acc[t][0] = __builtin_amdgcn_mfma_f32_16x16x32_bf16(wf0, xf0, acc[t][0], 0,0,0);
      acc[t][1] = __builtin_amdgcn_mfma_f32_16x16x32_bf16(wf0, xf1, acc[t][1], 0,0,0);
      acc[t][2] = __builtin_amdgcn_mfma_f32_16x16x32_bf16(wf1, xf0, acc[t][2], 0,0,0);
      acc[t][3] = __builtin_amdgcn_mfma_f32_16x16x32_bf16(wf1, xf1, acc[t][3], 0,0,0);
    }
    __syncthreads();
  }
  const int Wo = 2*Wi, HWo = 4*HWi;
  int co0 = n_base + n_off + quad*4, co1 = co0 + 16;
  float4v bv0 = *(const float4v*)(bias + co0);
  float4v bv1 = *(const float4v*)(bias + co1);
  int px0 = m_base + m_off + r16, px1 = px0 + 16;
  #pragma unroll
  for (int j = 0; j < 2; ++j){
    int p = j ? px1 : px0;
    int r = p / Wi, c = p - r*Wi;
    #pragma unroll
    for (int t = 0; t < 4; ++t){
      int opix = (2*r + (t>>1))*Wo + 2*c + (t&1);
      ushort* o = CC + ((size_t)b*HWo + opix)*Ctot;
      float4v vA = acc[t][0 + j] + bv0;   // co set 0
      float4v vB = acc[t][2 + j] + bv1;   // co set 1
      uint2v pA, pB;
      pA.x = (unsigned)f2b(vA.x) | ((unsigned)f2b(vA.y) << 16);
      pA.y = (unsigned)f2b(vA.z) | ((unsigned)f2b(vA.w) << 16);
      pB.x = (unsigned)f2b(vB.x) | ((unsigned)f2b(vB.y) << 16);
      pB.y = (unsigned)f2b(vB.z) | ((unsigned)f2b(vB.w) << 16);
      *(uint2v*)(o + co0) = pA;
      *(uint2v*)(o + co1) = pB;
    }
  }
}

// NCHW fp32 skip feature -> NHWC bf16 concat channels [Coff, Coff+Cf)
__global__ void k_feat2cc(const float* __restrict__ feat, ushort* __restrict__ cc,
                          int Cf, int Coff, int Ctot, int HW){
  __shared__ ushort t[32][33];
  int pb = blockIdx.x*32, cbs = blockIdx.y*32, b = blockIdx.z;
  int tx = threadIdx.x, ty = threadIdx.y;
  #pragma unroll
  for (int i = 0; i < 4; ++i){
    int c = cbs + ty + i*8;
    t[ty + i*8][tx] = f2b(feat[((size_t)(b*Cf) + c)*HW + pb + tx]);
  }
  __syncthreads();
  #pragma unroll
  for (int i = 0; i < 4; ++i){
    int p = pb + ty + i*8;
    cc[((size_t)b*HW + p)*Ctot + Coff + cbs + tx] = t[tx][ty + i*8];
  }
}

// BN stats phase 1: x fp32 NHWC, 64 blocks, partials per channel
__global__ void k_bnstats_nhwc(const float* __restrict__ x, float* __restrict__ part,
                               int C, int HW){
  int s = blockIdx.x, tid = threadIdx.x;
  int R = B_*HW;
  int chunk = R >> 6;           // R/64
  int G = 256 / C;              // 1,2,4
  int c = tid % C, g = tid / C;
  float s1 = 0.f, s2 = 0.f;
  for (int r = s*chunk + g; r < (s+1)*chunk; r += G){
    float v = x[(size_t)r*C + c];
    s1 += v; s2 += v*v;
  }
  __shared__ float h1[256], h2[256];
  h1[tid] = s1; h2[tid] = s2;
  __syncthreads();
  if (tid < C){
    float a = h1[tid], d = h2[tid];
    for (int gg = 1; gg < G; ++gg){ a += h1[tid + gg*C]; d += h2[tid + gg*C]; }
    part[(c*64 + s)*2]     = a;
    part[(c*64 + s)*2 + 1] = d;
  }
}

// BN finalize -> fused scale/shift
__global__ void k_bnfinal(const float* __restrict__ part, const float* __restrict__ g,
                          const float* __restrict__ bb, float* __restrict__ scale,
                          float* __restrict__ shift, int cnt){
  int c = blockIdx.x, t = threadIdx.x;  // 64 threads
  __shared__ float r1[64], r2[64];
  r1[t] = part[(c*64 + t)*2];
  r2[t] = part[(c*64 + t)*2 + 1];
  __syncthreads();
  for (int off = 32; off > 0; off >>= 1){
    if (t < off){ r1[t] += r1[t+off]; r2[t] += r2[t+off]; }
    __syncthreads();
  }
  if (t == 0){
    float m = r1[0]/cnt;
    float v = r2[0]/cnt - m*m;
    float sc = g[c]*rsqrtf(v + 1e-5f);
    scale[c] = sc;
    shift[c] = bb[c] - m*sc;
  }
}

// BN apply + ReLU, fp32 NHWC -> bf16 NHWC
__global__ void k_bnapply_nhwc(const float* __restrict__ x, ushort* __restrict__ y,
                               const float* __restrict__ scale,
                               const float* __restrict__ shift, int C, int n4){
  int i = blockIdx.x*256 + threadIdx.x;
  if (i >= n4) return;
  float4v v = *(const float4v*)(x + (size_t)4*i);
  int c0 = (4*i) % C;
  float4v sc = *(const float4v*)(scale + c0);
  float4v sh = *(const float4v*)(shift + c0);
  float r0 = fmaxf(v.x*sc.x + sh.x, 0.f);
  float r1 = fmaxf(v.y*sc.y + sh.y, 0.f);
  float r2 = fmaxf(v.z*sc.z + sh.z, 0.f);
  float r3 = fmaxf(v.w*sc.w + sh.w, 0.f);
  uint2v pk;
  pk.x = (unsigned)f2b(r0) | ((unsigned)f2b(r1) << 16);
  pk.y = (unsigned)f2b(r2) | ((unsigned)f2b(r3) << 16);
  *(uint2v*)(y + (size_t)4*i) = pk;
}

// final 1x1 conv (64ch NHWC bf16 -> 1) + sigmoid
__global__ void k_last_nhwc(const ushort* __restrict__ x, const float* __restrict__ lw,
                            const float* __restrict__ lb, float* __restrict__ out){
  __shared__ float wsm[64];
  int tid = threadIdx.x;
  if (tid < 64) wsm[tid] = lw[tid];
  __syncthreads();
  int i = blockIdx.x*256 + tid;          // over 16*16384 pixels
  const uint4v* xr = (const uint4v*)(x + (size_t)i*64);
  float acc = lb[0];
  #pragma unroll
  for (int q = 0; q < 8; ++q){
    uint4v u = xr[q];
    unsigned uu[4] = {u.x, u.y, u.z, u.w};
    #pragma unroll
    for (int k = 0; k < 4; ++k){
      acc += bits2f(uu[k] << 16)          * wsm[q*8 + 2*k];
      acc += bits2f(uu[k] & 0xffff0000u)  * wsm[q*8 + 2*k + 1];
    }
  }
  out[i] = 1.f/(1.f + __expf(-acc));
}

// ---------------- host ----------------
#define MBx 1048576ull

static inline void run_conv(const ushort* in, const float* w, ushort* W9,
                            float* out, int Cin, int Cout, int H, int W,
                            hipStream_t stream){
  int total = Cout*Cin*9;
  k_w9<<<(total+255)/256, 256, 0, stream>>>(w, W9, Cin, Cout);
  k_conv_nhwc<<<dim3(H*W/64, Cout/64, B_), 256, 0, stream>>>(in, W9, out, Cin, Cout, H, W);
}

static inline void run_bn(const float* x, ushort* y, float* part, float* scale, float* shift,
                          const float* g, const float* bb, int C, int HW, hipStream_t stream){
  k_bnstats_nhwc<<<64, 256, 0, stream>>>(x, part, C, HW);
  k_bnfinal<<<C, 64, 0, stream>>>(part, g, bb, scale, shift, B_*HW);
  int n4 = B_*HW*C/4;
  k_bnapply_nhwc<<<(n4+255)/256, 256, 0, stream>>>(x, y, scale, shift, C, n4);
}

extern "C" void kernel_launch(void* const* d_in, const int* in_sizes, int n_in,
                              void* d_out, int out_size, void* d_ws, size_t ws_size,
                              hipStream_t stream){
  const float* x     = (const float*)d_in[0];
  const float* feat0 = (const float*)d_in[1];
  const float* feat1 = (const float*)d_in[2];
  const float* feat2 = (const float*)d_in[3];
  const float* pos   = (const float*)d_in[4];
  const float* cb    = (const float*)d_in[5];
  const float* ln_g  = (const float*)d_in[6];
  const float* ln_b  = (const float*)d_in[7];
  const float* wqkv  = (const float*)d_in[8];
  const float* wo    = (const float*)d_in[9];
  const float* bo    = (const float*)d_in[10];
  const float* up_w0 = (const float*)d_in[11];
  const float* up_b0 = (const float*)d_in[12];
  const float* cw0a  = (const float*)d_in[13];
  const float* g0a   = (const float*)d_in[14];
  const float* b0a   = (const float*)d_in[15];
  const float* cw0b  = (const float*)d_in[16];
  const float* g0b   = (const float*)d_in[17];
  const float* b0b   = (const float*)d_in[18];
  const float* up_w1 = (const float*)d_in[19];
  const float* up_b1 = (const float*)d_in[20];
  const float* cw1a  = (const float*)d_in[21];
  const float* g1a   = (const float*)d_in[22];
  const float* b1a   = (const float*)d_in[23];
  const float* cw1b  = (const float*)d_in[24];
  const float* g1b   = (const float*)d_in[25];
  const float* b1b   = (const float*)d_in[26];
  const float* up_w2 = (const float*)d_in[27];
  const float* up_b2 = (const float*)d_in[28];
  const float* cw2a  = (const float*)d_in[29];
  const float* g2a   = (const float*)d_in[30];
  const float* b2a   = (const float*)d_in[31];
  const float* cw2b  = (const float*)d_in[32];
  const float* g2b   = (const float*)d_in[33];
  const float* b2b   = (const float*)d_in[34];
  const float* lw    = (const float*)d_in[35];
  const float* lb    = (const float*)d_in[36];

  char* ws = (char*)d_ws;
  // encoder/VQ scratch (region 0..134MB)
  float*  tok     = (float*) (ws);
  ushort* xn_hi   = (ushort*)(ws +  8388608ull);
  ushort* xn_lo   = (ushort*)(ws + 12582912ull);
  float*  qkv     = (float*) (ws + 16777216ull);
  ushort* at_hi   = (ushort*)(ws + 41943040ull);
  ushort* at_lo   = (ushort*)(ws + 46137344ull);
  ushort* tok_hi  = (ushort*)(ws + 50331648ull);
  ushort* tok_lo  = (ushort*)(ws + 54525952ull);
  ushort* Wq_hi   = (ushort*)(ws + 58720256ull);
  ushort* Wq_lo   = (ushort*)(ws + 77594624ull);
  ushort* Wo_hi   = (ushort*)(ws + 96468992ull);
  ushort* Wo_lo   = (ushort*)(ws + 102760448ull);
  ushort* cb_hi   = (ushort*)(ws + 109051904ull);
  ushort* cb_lo   = (ushort*)(ws + 111149056ull);
  float*  cnorm   = (float*) (ws + 113246208ull);
  int*    idx     = (int*)   (ws + 113254400ull);
  float*  d2      = (float*) (ws + 58720256ull);   // overlaps Wq (dead at VQ time)
  // tail: weights + bn scratch + y0
  ushort* W9   = (ushort*)(ws + 134*MBx);
  ushort* Wt4  = (ushort*)(ws + 137*MBx);
  float* bnp   = (float*) (ws + 138*MBx);
  float* bnsc  = (float*) (ws + 138*MBx + 524288);
  float* bnsh  = (float*) (ws + 138*MBx + 528384);
  ushort* y0   = (ushort*)(ws + 139*MBx);
  // decoder ping-pong (see round journal for liveness proof)
  ushort* cc0 = (ushort*)(ws + 146*MBx);
  float*  va0 = (float*) (ws + 163*MBx);
  ushort* xa0 = (ushort*)(ws + 180*MBx);
  float*  vb0 = (float*) (ws + 146*MBx);
  ushort* xb0 = (ushort*)(ws + 189*MBx);
  ushort* cc1 = (ushort*)(ws + 0*MBx);
  float*  va1 = (float*) (ws + 34*MBx);
  ushort* xa1 = (ushort*)(ws + 68*MBx);
  float*  vb1 = (float*) (ws + 85*MBx);
  ushort* xb1 = (ushort*)(ws + 146*MBx);
  ushort* cc2 = (ushort*)(ws + 0*MBx);
  float*  va2 = (float*) (ws + 67*MBx);
  ushort* xa2 = (ushort*)(ws + 146*MBx);
  float*  vb2 = (float*) (ws + 0*MBx);
  ushort* xb2 = (ushort*)(ws + 67*MBx);

  // ---- weight prep ----
  k_split_t<<<(DEPTH*D_*1536+255)/256, 256, 0, stream>>>(wqkv, Wq_hi, Wq_lo, DEPTH, D_, 1536);
  k_split_t<<<(DEPTH*D_*D_+255)/256, 256, 0, stream>>>(wo, Wo_hi, Wo_lo, DEPTH, D_, D_);
  k_split<<<(KCODE*D_+255)/256, 256, 0, stream>>>(cb, cb_hi, cb_lo, KCODE*D_);
  k_cnorm<<<KCODE, 256, 0, stream>>>(cb, cnorm);

  // ---- encoder ----
  k_tok_init<<<(B_*NTOK*D_)/256, 256, 0, stream>>>(x, pos, tok);
  for (int l = 0; l < DEPTH; ++l){
    k_ln_split<<<M_, 256, 0, stream>>>(tok, xn_hi, xn_lo, ln_g + l*D_, ln_b + l*D_);
    k_gemm_split<<<dim3(M_/64, 1536/64), 256, 0, stream>>>(
        xn_hi, xn_lo, Wq_hi + (size_t)l*1536*D_, Wq_lo + (size_t)l*1536*D_,
        qkv, nullptr, nullptr, M_, 1536, D_);
    k_attn2<<<dim3(HEADS, B_), 256, 0, stream>>>(qkv, at_hi, at_lo);
    k_gemm_split<<<dim3(M_/64, D_/64), 256, 0, stream>>>(
        at_hi, at_lo, Wo_hi + (size_t)l*D_*D_, Wo_lo + (size_t)l*D_*D_,
        tok, bo + l*D_, tok, M_, D_, D_);
  }

  // ---- VQ ----
  k_split<<<(M_*D_+255)/256, 256, 0, stream>>>(tok, tok_hi, tok_lo, M_*D_);
  k_gemm_split<<<dim3(M_/64, KCODE/64), 256, 0, stream>>>(
      tok_hi, tok_lo, cb_hi, cb_lo, d2, nullptr, nullptr, M_, KCODE, D_);
  k_argmin<<<M_, 256, 0, stream>>>(d2, cnorm, idx);
  k_gather_nhwc<<<(B_*NTOK*D_)/256, 256, 0, stream>>>(cb, idx, y0);

  // ---- decoder stage 0: 16x16 -> 32x32, Ctot=512 ----
  k_upw<<<(512*256*4+255)/256, 256, 0, stream>>>(up_w0, Wt4, 512, 256);
  k_upconv_nhwc<<<dim3(256/64, 256/64, B_), 256, 0, stream>>>(y0, Wt4, up_b0, cc0, 512, 256, 16, 16, 512);
  k_feat2cc<<<dim3(1024/32, 256/32, B_), dim3(32,8), 0, stream>>>(feat2, cc0, 256, 256, 512, 1024);
  run_conv(cc0, cw0a, W9, va0, 512, 256, 32, 32, stream);
  run_bn(va0, xa0, bnp, bnsc, bnsh, g0a, b0a, 256, 1024, stream);
  run_conv(xa0, cw0b, W9, vb0, 256, 256, 32, 32, stream);
  run_bn(vb0, xb0, bnp, bnsc, bnsh, g0b, b0b, 256, 1024, stream);

  // ---- decoder stage 1: 32x32 -> 64x64, Ctot=256 ----
  k_upw<<<(256*128*4+255)/256, 256, 0, stream>>>(up_w1, Wt4, 256, 128);
  k_upconv_nhwc<<<dim3(1024/64, 128/64, B_), 256, 0, stream>>>(xb0, Wt4, up_b1, cc1, 256, 128, 32, 32, 256);
  k_feat2cc<<<dim3(4096/32, 128/32, B_), dim3(32,8), 0, stream>>>(feat1, cc1, 128, 128, 256, 4096);
  run_conv(cc1, cw1a, W9, va1, 256, 128, 64, 64, stream);
  run_bn(va1, xa1, bnp, bnsc, bnsh, g1a, b1a, 128, 4096, stream);
  run_conv(xa1, cw1b, W9, vb1, 128, 128, 64, 64, stream);
  run_bn(vb1, xb1, bnp, bnsc, bnsh, g1b, b1b, 128, 4096, stream);

  // ---- decoder stage 2: 64x64 -> 128x128, Ctot=128 ----
  k_upw<<<(128*64*4+255)/256, 256, 0, stream>>>(up_w2, Wt4, 128, 64);
  k_upconv_nhwc<<<dim3(4096/64, 64/64, B_), 256, 0, stream>>>(xb1, Wt4, up_b2, cc2, 128, 64, 64, 64, 128);
  k_feat2cc<<<dim3(16384/32, 64/32, B_), dim3(32,8), 0, stream>>>(feat0, cc2, 64, 64, 128, 16384);
  run_conv(cc2, cw2a, W9, va2, 128, 64, 128, 128, stream);
  run_bn(va2, xa2, bnp, bnsc, bnsh, g2a, b2a, 64, 16384, stream);
  run_conv(xa2, cw2b, W9, vb2, 64, 64, 128, 128, stream);
  run_bn(vb2, xb2, bnp, bnsc, bnsh, g2b, b2b, 64, 16384, stream);

  // ---- head ----
  k_last_nhwc<<<(B_*16384)/256, 256, 0, stream>>>(xb2, lw, lb, (float*)d_out);
}

// Round 7
// 3210.042 us; speedup vs baseline: 1.2805x; 1.2805x over previous
//
#include <hip/hip_runtime.h>

#define B_    16
#define NTOK  256
#define D_    512
#define HEADS 16
#define DH    32
#define DEPTH 12
#define KCODE 2048
#define M_    (B_*NTOK)   // 4096 token rows
#define BN_S  512         // BN partial blocks

typedef __attribute__((ext_vector_type(8))) short short8;     // 8 bf16 (4 VGPRs)
typedef __attribute__((ext_vector_type(4))) float float4v;
typedef __attribute__((ext_vector_type(4))) unsigned int uint4v;
typedef __attribute__((ext_vector_type(2))) unsigned int uint2v;
typedef unsigned short ushort;

__device__ __forceinline__ ushort f2b(float f){   // fp32 -> bf16 RNE
  union { float f; unsigned u; } v; v.f = f;
  unsigned r = v.u + 0x7FFFu + ((v.u >> 16) & 1u);
  return (ushort)(r >> 16);
}
__device__ __forceinline__ float b2f(ushort h){
  union { unsigned u; float f; } v; v.u = ((unsigned)h) << 16; return v.f;
}
__device__ __forceinline__ float bits2f(unsigned u){
  union { unsigned u; float f; } v; v.u = u; return v.f;
}

// ---------------- prep kernels ----------------

__global__ void k_tok_init(const float* __restrict__ x, const float* __restrict__ pos,
                           float* __restrict__ tok){
  int i = blockIdx.x*256 + threadIdx.x;
  if (i >= B_*NTOK*D_) return;
  int d = i % D_; int r = i / D_; int t = r % NTOK; int b = r / NTOK;
  tok[i] = x[(b*D_ + d)*NTOK + t] + pos[t*D_ + d];
}

__global__ void k_split(const float* __restrict__ src, ushort* __restrict__ oh,
                        ushort* __restrict__ ol, int n){
  int i = blockIdx.x*256 + threadIdx.x;
  if (i >= n) return;
  float v = src[i];
  ushort h = f2b(v);
  oh[i] = h; ol[i] = f2b(v - b2f(h));
}

// split + transpose: src [L][K][N] f32 -> dst hi/lo [L][N][K] bf16
__global__ void k_split_t(const float* __restrict__ src, ushort* __restrict__ oh,
                          ushort* __restrict__ ol, int L, int K, int N){
  int i = blockIdx.x*256 + threadIdx.x;
  if (i >= L*K*N) return;
  int KN = K*N;
  int l = i / KN; int r = i - l*KN;
  int k = r / N;  int n = r - k*N;
  float v = src[i];
  ushort h = f2b(v);
  size_t o = (size_t)l*KN + (size_t)n*K + k;
  oh[o] = h; ol[o] = f2b(v - b2f(h));
}

// conv weights: [Cout][Cin][3][3] f32 -> W9 [9tap][Cout][Cin] bf16
__global__ void k_w9(const float* __restrict__ w, ushort* __restrict__ W9,
                     int Cin, int Cout){
  int i = blockIdx.x*256 + threadIdx.x;
  if (i >= Cout*Cin*9) return;
  int co = i / (Cin*9); int r = i - co*(Cin*9);
  int ci = r / 9; int tap = r - ci*9;
  W9[((size_t)tap*Cout + co)*Cin + ci] = f2b(w[i]);
}

// upconv weights: [Cin][Cout][2][2] f32 -> Wt4 [tap][Cout][Cin] bf16
__global__ void k_upw(const float* __restrict__ w, ushort* __restrict__ Wt4,
                      int Cin, int Cout){
  int i = blockIdx.x*256 + threadIdx.x;
  if (i >= Cin*Cout*4) return;
  int ci = i / (Cout*4); int r = i - ci*(Cout*4);
  int co = r >> 2; int tap = r & 3;
  Wt4[((size_t)tap*Cout + co)*Cin + ci] = f2b(w[i]);
}

// LayerNorm fused with bf16 hi/lo split
__global__ void k_ln_split(const float* __restrict__ in, ushort* __restrict__ oh,
                           ushort* __restrict__ ol, const float* __restrict__ g,
                           const float* __restrict__ bta){
  int row = blockIdx.x; int t = threadIdx.x;
  const float* xr = in + (size_t)row*D_;
  float x0 = xr[t], x1 = xr[t+256];
  __shared__ float r1[256], r2[256];
  r1[t] = x0+x1; r2[t] = x0*x0 + x1*x1;
  __syncthreads();
  for (int off=128; off>0; off>>=1){
    if (t<off){ r1[t]+=r1[t+off]; r2[t]+=r2[t+off]; }
    __syncthreads();
  }
  float mean = r1[0] * (1.f/D_);
  float var  = r2[0] * (1.f/D_) - mean*mean;
  float inv  = rsqrtf(var + 1e-5f);
  float y0 = (x0-mean)*inv*g[t]     + bta[t];
  float y1 = (x1-mean)*inv*g[t+256] + bta[t+256];
  size_t o = (size_t)row*D_;
  ushort h0 = f2b(y0), h1 = f2b(y1);
  oh[o+t] = h0;     ol[o+t]     = f2b(y0 - b2f(h0));
  oh[o+t+256] = h1; ol[o+t+256] = f2b(y1 - b2f(h1));
}

// ---------------- split-bf16 MFMA GEMM (3-term, fp32-accurate) ----------------
__global__ __launch_bounds__(256) void k_gemm_split(
    const ushort* __restrict__ Ah, const ushort* __restrict__ Al,
    const ushort* __restrict__ Bh, const ushort* __restrict__ Bl,
    float* __restrict__ C, const float* __restrict__ bias,
    const float* __restrict__ resid, int M, int N, int K){
  __shared__ ushort Ash[64][40], Asl[64][40], Bsh[64][40], Bsl[64][40];
  const int tid = threadIdx.x;
  const int m_base = blockIdx.x*64, n_base = blockIdx.y*64;
  const int lane = tid & 63, wv = tid >> 6;
  const int quad = lane >> 4, r16 = lane & 15;
  const int m_off = (wv & 1)*32, n_off = (wv >> 1)*32;
  const int srow = tid & 63, skq = tid >> 6;
  const size_t arow = (size_t)(m_base + srow)*K + skq*8;
  const size_t brow = (size_t)(n_base + srow)*K + skq*8;
  float4v acc00={}, acc01={}, acc10={}, acc11={};
  for (int k0 = 0; k0 < K; k0 += 32){
    *(uint4v*)&Ash[srow][skq*8] = *(const uint4v*)(Ah + arow + k0);
    *(uint4v*)&Asl[srow][skq*8] = *(const uint4v*)(Al + arow + k0);
    *(uint4v*)&Bsh[srow][skq*8] = *(const uint4v*)(Bh + brow + k0);
    *(uint4v*)&Bsl[srow][skq*8] = *(const uint4v*)(Bl + brow + k0);
    __syncthreads();
    short8 afh0 = *(const short8*)&Ash[m_off      + r16][quad*8];
    short8 afh1 = *(const short8*)&Ash[m_off + 16 + r16][quad*8];
    short8 afl0 = *(const short8*)&Asl[m_off      + r16][quad*8];
    short8 afl1 = *(const short8*)&Asl[m_off + 16 + r16][quad*8];
    short8 bfh0 = *(const short8*)&Bsh[n_off      + r16][quad*8];
    short8 bfh1 = *(const short8*)&Bsh[n_off + 16 + r16][quad*8];
    short8 bfl0 = *(const short8*)&Bsl[n_off      + r16][quad*8];
    short8 bfl1 = *(const short8*)&Bsl[n_off + 16 + r16][quad*8];
    acc00 = __builtin_amdgcn_mfma_f32_16x16x32_bf16(bfh0, afh0, acc00, 0,0,0);
    acc00 = __builtin_amdgcn_mfma_f32_16x16x32_bf16(bfh0, afl0, acc00, 0,0,0);
    acc00 = __builtin_amdgcn_mfma_f32_16x16x32_bf16(bfl0, afh0, acc00, 0,0,0);
    acc01 = __builtin_amdgcn_mfma_f32_16x16x32_bf16(bfh1, afh0, acc01, 0,0,0);
    acc01 = __builtin_amdgcn_mfma_f32_16x16x32_bf16(bfh1, afl0, acc01, 0,0,0);
    acc01 = __builtin_amdgcn_mfma_f32_16x16x32_bf16(bfl1, afh0, acc01, 0,0,0);
    acc10 = __builtin_amdgcn_mfma_f32_16x16x32_bf16(bfh0, afh1, acc10, 0,0,0);
    acc10 = __builtin_amdgcn_mfma_f32_16x16x32_bf16(bfh0, afl1, acc10, 0,0,0);
    acc10 = __builtin_amdgcn_mfma_f32_16x16x32_bf16(bfl0, afh1, acc10, 0,0,0);
    acc11 = __builtin_amdgcn_mfma_f32_16x16x32_bf16(bfh1, afh1, acc11, 0,0,0);
    acc11 = __builtin_amdgcn_mfma_f32_16x16x32_bf16(bfh1, afl1, acc11, 0,0,0);
    acc11 = __builtin_amdgcn_mfma_f32_16x16x32_bf16(bfl1, afh1, acc11, 0,0,0);
    __syncthreads();
  }
  int m0 = m_base + m_off + r16;
  int n0 = n_base + n_off + quad*4;
  float4v bv0 = {}, bv1 = {};
  if (bias){ bv0 = *(const float4v*)(bias + n0); bv1 = *(const float4v*)(bias + n0 + 16); }
  float4v v00 = acc00 + bv0, v01 = acc01 + bv1, v10 = acc10 + bv0, v11 = acc11 + bv1;
  if (resid){
    v00 += *(const float4v*)(resid + (size_t)m0*N + n0);
    v01 += *(const float4v*)(resid + (size_t)m0*N + n0 + 16);
    v10 += *(const float4v*)(resid + (size_t)(m0+16)*N + n0);
    v11 += *(const float4v*)(resid + (size_t)(m0+16)*N + n0 + 16);
  }
  *(float4v*)(C + (size_t)m0*N + n0)          = v00;
  *(float4v*)(C + (size_t)m0*N + n0 + 16)     = v01;
  *(float4v*)(C + (size_t)(m0+16)*N + n0)     = v10;
  *(float4v*)(C + (size_t)(m0+16)*N + n0 + 16)= v11;
}

// ---------------- attention: one block per (b,h), K/V in LDS ----------------
__global__ __launch_bounds__(256) void k_attn2(const float* __restrict__ qkv,
                                               ushort* __restrict__ oh,
                                               ushort* __restrict__ ol){
  __shared__ float4v ks[NTOK*8];
  __shared__ float4v vs[NTOK*8];
  const int h = blockIdx.x, b = blockIdx.y, t = threadIdx.x;
  const float* base = qkv + (size_t)b*NTOK*1536;
  const int koff = 512 + h*DH, voff = 1024 + h*DH;
  for (int i = t; i < NTOK*8; i += 256){
    int j = i >> 3, d4 = i & 7;
    ks[i] = *(const float4v*)(base + (size_t)j*1536 + koff + d4*4);
    vs[i] = *(const float4v*)(base + (size_t)j*1536 + voff + d4*4);
  }
  float4v q8[8];
  const float* qrow = base + (size_t)t*1536 + h*DH;
  #pragma unroll
  for (int d4 = 0; d4 < 8; ++d4) q8[d4] = *(const float4v*)(qrow + d4*4);
  __syncthreads();
  float4v o8[8];
  #pragma unroll
  for (int d4 = 0; d4 < 8; ++d4) o8[d4] = float4v{0.f,0.f,0.f,0.f};
  float l = 0.f;
  for (int j = 0; j < NTOK; ++j){
    float s = 0.f;
    #pragma unroll
    for (int d4 = 0; d4 < 8; ++d4){
      float4v kk = ks[j*8 + d4];
      s += q8[d4].x*kk.x + q8[d4].y*kk.y + q8[d4].z*kk.z + q8[d4].w*kk.w;
    }
    float e = __expf(s * 0.17677669529663689f);
    l += e;
    #pragma unroll
    for (int d4 = 0; d4 < 8; ++d4){
      float4v vv = vs[j*8 + d4];
      o8[d4].x += e*vv.x; o8[d4].y += e*vv.y; o8[d4].z += e*vv.z; o8[d4].w += e*vv.w;
    }
  }
  float inv = 1.f / l;
  size_t ob = (size_t)(b*NTOK + t)*D_ + h*DH;
  #pragma unroll
  for (int d4 = 0; d4 < 8; ++d4){
    float vals[4] = {o8[d4].x*inv, o8[d4].y*inv, o8[d4].z*inv, o8[d4].w*inv};
    #pragma unroll
    for (int r = 0; r < 4; ++r){
      ushort hh = f2b(vals[r]);
      oh[ob + d4*4 + r] = hh;
      ol[ob + d4*4 + r] = f2b(vals[r] - b2f(hh));
    }
  }
}

// ---------------- VQ ----------------
__global__ void k_cnorm(const float* __restrict__ cb, float* __restrict__ cnorm){
  int k = blockIdx.x, t = threadIdx.x;
  float v1 = cb[(size_t)k*D_ + t];
  float v2 = cb[(size_t)k*D_ + t + 256];
  __shared__ float r[256];
  r[t] = v1*v1 + v2*v2;
  __syncthreads();
  for (int off=128; off>0; off>>=1){
    if (t<off) r[t]+=r[t+off];
    __syncthreads();
  }
  if (t==0) cnorm[k] = r[0];
}

__global__ void k_argmin(const float* __restrict__ d2, const float* __restrict__ cnorm,
                         int* __restrict__ idx){
  int m = blockIdx.x, t = threadIdx.x;
  float best = 3.4e38f; int bk = 0;
  for (int k = t; k < KCODE; k += 256){
    float s = cnorm[k] - 2.f*d2[(size_t)m*KCODE + k];
    if (s < best){ best = s; bk = k; }
  }
  __shared__ float bs[256]; __shared__ int bi[256];
  bs[t]=best; bi[t]=bk;
  __syncthreads();
  for (int off=128; off>0; off>>=1){
    if (t<off){
      if (bs[t+off] < bs[t] || (bs[t+off]==bs[t] && bi[t+off]<bi[t])){
        bs[t]=bs[t+off]; bi[t]=bi[t+off];
      }
    }
    __syncthreads();
  }
  if (t==0) idx[m] = bi[0];
}

// y0 NHWC bf16: y0[b][t][d] = codebook[idx[b,t]][d]
__global__ void k_gather_nhwc(const float* __restrict__ cb, const int* __restrict__ idx,
                              ushort* __restrict__ y0){
  int i = blockIdx.x*256 + threadIdx.x;
  if (i >= B_*NTOK*D_) return;
  int d = i % D_; int r = i / D_; int t = r % NTOK; int b = r / NTOK;
  y0[i] = f2b(cb[(size_t)idx[b*NTOK + t]*D_ + d]);
}

// ---------------- decoder (NHWC bf16) ----------------

// 3x3 conv pad1 implicit GEMM, per-tap K loop.
__global__ __launch_bounds__(256) void k_conv_nhwc(
    const ushort* __restrict__ X, const ushort* __restrict__ W9,
    float* __restrict__ Y, int Cin, int Cout, int H, int W){
  __shared__ ushort Xs[64][40], Ws[64][40];
  const int HW = H*W;
  const int tid = threadIdx.x;
  const int b = blockIdx.z;
  const int m_base = blockIdx.x*64;   // pixel tile
  const int n_base = blockIdx.y*64;   // cout tile
  const int lane = tid & 63, wv = tid >> 6;
  const int quad = lane >> 4, r16 = lane & 15;
  const int m_off = (wv & 1)*32, n_off = (wv >> 1)*32;
  const int srow = tid & 63, skq = tid >> 6;
  const int p = m_base + srow;
  const int pr = p / W, pc = p - pr*W;
  const ushort* Xb = X + (size_t)b*HW*Cin;
  const uint4v zz = {};
  float4v a00={}, a01={}, a10={}, a11={};
  for (int tap = 0; tap < 9; ++tap){
    int kh = tap/3, kw = tap - kh*3;
    int ih = pr + kh - 1, iw = pc + kw - 1;
    bool ok = (ih >= 0 && ih < H && iw >= 0 && iw < W);
    const ushort* xrow = Xb + (size_t)(ih*W + iw)*Cin + skq*8;
    const ushort* wrow = W9 + ((size_t)tap*Cout + n_base + srow)*Cin + skq*8;
    for (int k0 = 0; k0 < Cin; k0 += 32){
      uint4v xv = ok ? *(const uint4v*)(xrow + k0) : zz;
      *(uint4v*)&Xs[srow][skq*8] = xv;
      *(uint4v*)&Ws[srow][skq*8] = *(const uint4v*)(wrow + k0);
      __syncthreads();
      short8 xf0 = *(const short8*)&Xs[m_off      + r16][quad*8];
      short8 xf1 = *(const short8*)&Xs[m_off + 16 + r16][quad*8];
      short8 wf0 = *(const short8*)&Ws[n_off      + r16][quad*8];
      short8 wf1 = *(const short8*)&Ws[n_off + 16 + r16][quad*8];
      a00 = __builtin_amdgcn_mfma_f32_16x16x32_bf16(wf0, xf0, a00, 0,0,0);
      a01 = __builtin_amdgcn_mfma_f32_16x16x32_bf16(wf0, xf1, a01, 0,0,0);
      a10 = __builtin_amdgcn_mfma_f32_16x16x32_bf16(wf1, xf0, a10, 0,0,0);
      a11 = __builtin_amdgcn_mfma_f32_16x16x32_bf16(wf1, xf1, a11, 0,0,0);
      __syncthreads();
    }
  }
  float* Yb = Y + (size_t)b*HW*Cout;
  int px0 = m_base + m_off + r16, px1 = px0 + 16;
  int co0 = n_base + n_off + quad*4, co1 = co0 + 16;
  *(float4v*)(Yb + (size_t)px0*Cout + co0) = a00;
  *(float4v*)(Yb + (size_t)px1*Cout + co0) = a01;
  *(float4v*)(Yb + (size_t)px0*Cout + co1) = a10;
  *(float4v*)(Yb + (size_t)px1*Cout + co1) = a11;
}

// ConvTranspose2d k=2 s=2: X staged once per K-chunk, 4 weight taps share it.
__global__ __launch_bounds__(256) void k_upconv_nhwc(
    const ushort* __restrict__ X, const ushort* __restrict__ Wt4,
    const float* __restrict__ bias, ushort* __restrict__ CC,
    int Cin, int Cout, int Hi, int Wi, int Ctot){
  __shared__ ushort Xs[64][40], Ws[4][64][40];
  const int HWi = Hi*Wi;
  const int tid = threadIdx.x;
  const int b = blockIdx.z;
  const int m_base = blockIdx.x*64;
  const int n_base = blockIdx.y*64;
  const int lane = tid & 63, wv = tid >> 6;
  const int quad = lane >> 4, r16 = lane & 15;
  const int m_off = (wv & 1)*32, n_off = (wv >> 1)*32;
  const int srow = tid & 63, skq = tid >> 6;
  const ushort* xrow = X + ((size_t)b*HWi + m_base + srow)*Cin + skq*8;
  const ushort* w0 = Wt4 + ((size_t)0*Cout + n_base + srow)*Cin + skq*8;
  const ushort* w1 = Wt4 + ((size_t)1*Cout + n_base + srow)*Cin + skq*8;
  const ushort* w2 = Wt4 + ((size_t)2*Cout + n_base + srow)*Cin + skq*8;
  const ushort* w3 = Wt4 + ((size_t)3*Cout + n_base + srow)*Cin + skq*8;
  float4v acc[4][4];
  #pragma unroll
  for (int t = 0; t < 4; ++t)
    #pragma unroll
    for (int q = 0; q < 4; ++q) acc[t][q] = float4v{0.f,0.f,0.f,0.f};
  for (int k0 = 0; k0 < Cin; k0 += 32){
    *(uint4v*)&Xs[srow][skq*8]    = *(const uint4v*)(xrow + k0);
    *(uint4v*)&Ws[0][srow][skq*8] = *(const uint4v*)(w0 + k0);
    *(uint4v*)&Ws[1][srow][skq*8] = *(const uint4v*)(w1 + k0);
    *(uint4v*)&Ws[2][srow][skq*8] = *(const uint4v*)(w2 + k0);
    *(uint4v*)&Ws[3][srow][skq*8] = *(const uint4v*)(w3 + k0);
    __syncthreads();
    short8 xf0 = *(const short8*)&Xs[m_off      + r16][quad*8];
    short8 xf1 = *(const short8*)&Xs[m_off + 16 + r16][quad*8];
    #pragma unroll
    for (int t = 0; t < 4; ++t){
      short8 wf0 = *(const short8*)&Ws[t][n_off      + r16][quad*8];
      short8 wf1 = *(const short8*)&Ws[t][n_off + 16 + r16][quad*8];
      acc[t][0] = __builtin_amdgcn_mfma_f32_16x16x32_bf16(wf0, xf0, acc[t][0], 0,0,0);
      acc[t][1] = __builtin_amdgcn_mfma_f32_16x16x32_bf16(wf0, xf1, acc[t][1], 0,0,0);
      acc[t][2] = __builtin_amdgcn_mfma_f32_16x16x32_bf16(wf1, xf0, acc[t][2], 0,0,0);
      acc[t][3] = __builtin_amdgcn_mfma_f32_16x16x32_bf16(wf1, xf1, acc[t][3], 0,0,0);
    }
    __syncthreads();
  }
  const int Wo = 2*Wi, HWo = 4*HWi;
  int co0 = n_base + n_off + quad*4, co1 = co0 + 16;
  float4v bv0 = *(const float4v*)(bias + co0);
  float4v bv1 = *(const float4v*)(bias + co1);
  int px0 = m_base + m_off + r16, px1 = px0 + 16;
  #pragma unroll
  for (int j = 0; j < 2; ++j){
    int p = j ? px1 : px0;
    int r = p / Wi, c = p - r*Wi;
    #pragma unroll
    for (int t = 0; t < 4; ++t){
      int opix = (2*r + (t>>1))*Wo + 2*c + (t&1);
      ushort* o = CC + ((size_t)b*HWo + opix)*Ctot;
      float4v vA = acc[t][0 + j] + bv0;
      float4v vB = acc[t][2 + j] + bv1;
      uint2v pA, pB;
      pA.x = (unsigned)f2b(vA.x) | ((unsigned)f2b(vA.y) << 16);
      pA.y = (unsigned)f2b(vA.z) | ((unsigned)f2b(vA.w) << 16);
      pB.x = (unsigned)f2b(vB.x) | ((unsigned)f2b(vB.y) << 16);
      pB.y = (unsigned)f2b(vB.z) | ((unsigned)f2b(vB.w) << 16);
      *(uint2v*)(o + co0) = pA;
      *(uint2v*)(o + co1) = pB;
    }
  }
}

// NCHW fp32 skip feature -> NHWC bf16 concat channels [Coff, Coff+Cf)
__global__ void k_feat2cc(const float* __restrict__ feat, ushort* __restrict__ cc,
                          int Cf, int Coff, int Ctot, int HW){
  __shared__ ushort t[32][33];
  int pb = blockIdx.x*32, cbs = blockIdx.y*32, b = blockIdx.z;
  int tx = threadIdx.x, ty = threadIdx.y;
  #pragma unroll
  for (int i = 0; i < 4; ++i){
    int c = cbs + ty + i*8;
    t[ty + i*8][tx] = f2b(feat[((size_t)(b*Cf) + c)*HW + pb + tx]);
  }
  __syncthreads();
  #pragma unroll
  for (int i = 0; i < 4; ++i){
    int p = pb + ty + i*8;
    cc[((size_t)b*HW + p)*Ctot + Coff + cbs + tx] = t[tx][ty + i*8];
  }
}

// BN stats phase 1: BN_S blocks, float4 channel-quads, LDS cross-group reduce.
// part layout: part[c*BN_S + s] (sum), part[(C + c)*BN_S + s] (sumsq)
__global__ __launch_bounds__(256) void k_bnstats_nhwc(
    const float* __restrict__ x, float* __restrict__ part, int C, int HW){
  const int s = blockIdx.x, tid = threadIdx.x;
  const int R = B_*HW;
  const int chunk = R / BN_S;          // rows per block (divisible for all stages)
  const int L = C >> 2;                // float4 lanes per row: 16/32/64
  const int G = 256 / L;               // rows in flight: 16/8/4
  const int c4 = tid % L, g = tid / L;
  float4v a = {}, q = {};
  const float* xb = x + (size_t)(s*chunk)*C + 4*c4;
  for (int r = g; r < chunk; r += G){
    float4v v = *(const float4v*)(xb + (size_t)r*C);
    a += v; q += v*v;
  }
  __shared__ float4v h1[256], h2[256];
  h1[tid] = a; h2[tid] = q;
  __syncthreads();
  if (tid < L){
    float4v ra = h1[tid], rq = h2[tid];
    for (int gg = 1; gg < G; ++gg){ ra += h1[tid + gg*L]; rq += h2[tid + gg*L]; }
    int c0 = 4*c4;
    part[(size_t)(c0+0)*BN_S + s] = ra.x;
    part[(size_t)(c0+1)*BN_S + s] = ra.y;
    part[(size_t)(c0+2)*BN_S + s] = ra.z;
    part[(size_t)(c0+3)*BN_S + s] = ra.w;
    part[(size_t)(C+c0+0)*BN_S + s] = rq.x;
    part[(size_t)(C+c0+1)*BN_S + s] = rq.y;
    part[(size_t)(C+c0+2)*BN_S + s] = rq.z;
    part[(size_t)(C+c0+3)*BN_S + s] = rq.w;
  }
}

// BN finalize: one block per channel reduces BN_S partials -> scale/shift
__global__ void k_bnfinal(const float* __restrict__ part, const float* __restrict__ g,
                          const float* __restrict__ bb, float* __restrict__ scale,
                          float* __restrict__ shift, int C, int cnt){
  int c = blockIdx.x, t = threadIdx.x;  // 256 threads
  __shared__ float r1[256], r2[256];
  r1[t] = part[(size_t)c*BN_S + t]       + part[(size_t)c*BN_S + t + 256];
  r2[t] = part[(size_t)(C + c)*BN_S + t] + part[(size_t)(C + c)*BN_S + t + 256];
  __syncthreads();
  for (int off = 128; off > 0; off >>= 1){
    if (t < off){ r1[t] += r1[t+off]; r2[t] += r2[t+off]; }
    __syncthreads();
  }
  if (t == 0){
    float m = r1[0]/cnt;
    float v = r2[0]/cnt - m*m;
    float sc = g[c]*rsqrtf(v + 1e-5f);
    scale[c] = sc;
    shift[c] = bb[c] - m*sc;
  }
}

// BN apply + ReLU, fp32 NHWC -> bf16 NHWC
__global__ void k_bnapply_nhwc(const float* __restrict__ x, ushort* __restrict__ y,
                               const float* __restrict__ scale,
                               const float* __restrict__ shift, int C, int n4){
  int i = blockIdx.x*256 + threadIdx.x;
  if (i >= n4) return;
  float4v v = *(const float4v*)(x + (size_t)4*i);
  int c0 = (4*i) % C;
  float4v sc = *(const float4v*)(scale + c0);
  float4v sh = *(const float4v*)(shift + c0);
  float r0 = fmaxf(v.x*sc.x + sh.x, 0.f);
  float r1 = fmaxf(v.y*sc.y + sh.y, 0.f);
  float r2 = fmaxf(v.z*sc.z + sh.z, 0.f);
  float r3 = fmaxf(v.w*sc.w + sh.w, 0.f);
  uint2v pk;
  pk.x = (unsigned)f2b(r0) | ((unsigned)f2b(r1) << 16);
  pk.y = (unsigned)f2b(r2) | ((unsigned)f2b(r3) << 16);
  *(uint2v*)(y + (size_t)4*i) = pk;
}

// final 1x1 conv (64ch NHWC bf16 -> 1) + sigmoid
__global__ void k_last_nhwc(const ushort* __restrict__ x, const float* __restrict__ lw,
                            const float* __restrict__ lb, float* __restrict__ out){
  __shared__ float wsm[64];
  int tid = threadIdx.x;
  if (tid < 64) wsm[tid] = lw[tid];
  __syncthreads();
  int i = blockIdx.x*256 + tid;
  const uint4v* xr = (const uint4v*)(x + (size_t)i*64);
  float acc = lb[0];
  #pragma unroll
  for (int q = 0; q < 8; ++q){
    uint4v u = xr[q];
    unsigned uu[4] = {u.x, u.y, u.z, u.w};
    #pragma unroll
    for (int k = 0; k < 4; ++k){
      acc += bits2f(uu[k] << 16)          * wsm[q*8 + 2*k];
      acc += bits2f(uu[k] & 0xffff0000u)  * wsm[q*8 + 2*k + 1];
    }
  }
  out[i] = 1.f/(1.f + __expf(-acc));
}

// ---------------- host ----------------
#define MBx 1048576ull

static inline void run_conv(const ushort* in, const float* w, ushort* W9,
                            float* out, int Cin, int Cout, int H, int W,
                            hipStream_t stream){
  int total = Cout*Cin*9;
  k_w9<<<(total+255)/256, 256, 0, stream>>>(w, W9, Cin, Cout);
  k_conv_nhwc<<<dim3(H*W/64, Cout/64, B_), 256, 0, stream>>>(in, W9, out, Cin, Cout, H, W);
}

static inline void run_bn(const float* x, ushort* y, float* part, float* scale, float* shift,
                          const float* g, const float* bb, int C, int HW, hipStream_t stream){
  k_bnstats_nhwc<<<BN_S, 256, 0, stream>>>(x, part, C, HW);
  k_bnfinal<<<C, 256, 0, stream>>>(part, g, bb, scale, shift, C, B_*HW);
  int n4 = B_*HW*C/4;
  k_bnapply_nhwc<<<(n4+255)/256, 256, 0, stream>>>(x, y, scale, shift, C, n4);
}

extern "C" void kernel_launch(void* const* d_in, const int* in_sizes, int n_in,
                              void* d_out, int out_size, void* d_ws, size_t ws_size,
                              hipStream_t stream){
  const float* x     = (const float*)d_in[0];
  const float* feat0 = (const float*)d_in[1];
  const float* feat1 = (const float*)d_in[2];
  const float* feat2 = (const float*)d_in[3];
  const float* pos   = (const float*)d_in[4];
  const float* cb    = (const float*)d_in[5];
  const float* ln_g  = (const float*)d_in[6];
  const float* ln_b  = (const float*)d_in[7];
  const float* wqkv  = (const float*)d_in[8];
  const float* wo    = (const float*)d_in[9];
  const float* bo    = (const float*)d_in[10];
  const float* up_w0 = (const float*)d_in[11];
  const float* up_b0 = (const float*)d_in[12];
  const float* cw0a  = (const float*)d_in[13];
  const float* g0a   = (const float*)d_in[14];
  const float* b0a   = (const float*)d_in[15];
  const float* cw0b  = (const float*)d_in[16];
  const float* g0b   = (const float*)d_in[17];
  const float* b0b   = (const float*)d_in[18];
  const float* up_w1 = (const float*)d_in[19];
  const float* up_b1 = (const float*)d_in[20];
  const float* cw1a  = (const float*)d_in[21];
  const float* g1a   = (const float*)d_in[22];
  const float* b1a   = (const float*)d_in[23];
  const float* cw1b  = (const float*)d_in[24];
  const float* g1b   = (const float*)d_in[25];
  const float* b1b   = (const float*)d_in[26];
  const float* up_w2 = (const float*)d_in[27];
  const float* up_b2 = (const float*)d_in[28];
  const float* cw2a  = (const float*)d_in[29];
  const float* g2a   = (const float*)d_in[30];
  const float* b2a   = (const float*)d_in[31];
  const float* cw2b  = (const float*)d_in[32];
  const float* g2b   = (const float*)d_in[33];
  const float* b2b   = (const float*)d_in[34];
  const float* lw    = (const float*)d_in[35];
  const float* lb    = (const float*)d_in[36];

  char* ws = (char*)d_ws;
  // encoder/VQ scratch (region 0..134MB)
  float*  tok     = (float*) (ws);
  ushort* xn_hi   = (ushort*)(ws +  8388608ull);
  ushort* xn_lo   = (ushort*)(ws + 12582912ull);
  float*  qkv     = (float*) (ws + 16777216ull);
  ushort* at_hi   = (ushort*)(ws + 41943040ull);
  ushort* at_lo   = (ushort*)(ws + 46137344ull);
  ushort* tok_hi  = (ushort*)(ws + 50331648ull);
  ushort* tok_lo  = (ushort*)(ws + 54525952ull);
  ushort* Wq_hi   = (ushort*)(ws + 58720256ull);
  ushort* Wq_lo   = (ushort*)(ws + 77594624ull);
  ushort* Wo_hi   = (ushort*)(ws + 96468992ull);
  ushort* Wo_lo   = (ushort*)(ws + 102760448ull);
  ushort* cb_hi   = (ushort*)(ws + 109051904ull);
  ushort* cb_lo   = (ushort*)(ws + 111149056ull);
  float*  cnorm   = (float*) (ws + 113246208ull);
  int*    idx     = (int*)   (ws + 113254400ull);
  float*  d2      = (float*) (ws + 58720256ull);   // overlaps Wq (dead at VQ time)
  // tail: weights + bn scratch + y0
  ushort* W9   = (ushort*)(ws + 134*MBx);          // 2.25 MB max
  float* bnsc  = (float*) (ws + 136*MBx + 524288); // 1 KB
  float* bnsh  = (float*) (ws + 136*MBx + 528384); // 1 KB
  ushort* Wt4  = (ushort*)(ws + 137*MBx);          // 1 MB max
  float* bnp   = (float*) (ws + 138*MBx);          // 2*C*BN_S*4 = 1 MB max
  ushort* y0   = (ushort*)(ws + 139*MBx);
  // decoder ping-pong
  ushort* cc0 = (ushort*)(ws + 146*MBx);
  float*  va0 = (float*) (ws + 163*MBx);
  ushort* xa0 = (ushort*)(ws + 180*MBx);
  float*  vb0 = (float*) (ws + 146*MBx);
  ushort* xb0 = (ushort*)(ws + 189*MBx);
  ushort* cc1 = (ushort*)(ws + 0*MBx);
  float*  va1 = (float*) (ws + 34*MBx);
  ushort* xa1 = (ushort*)(ws + 68*MBx);
  float*  vb1 = (float*) (ws + 85*MBx);
  ushort* xb1 = (ushort*)(ws + 146*MBx);
  ushort* cc2 = (ushort*)(ws + 0*MBx);
  float*  va2 = (float*) (ws + 67*MBx);
  ushort* xa2 = (ushort*)(ws + 146*MBx);
  float*  vb2 = (float*) (ws + 0*MBx);
  ushort* xb2 = (ushort*)(ws + 67*MBx);

  // ---- weight prep ----
  k_split_t<<<(DEPTH*D_*1536+255)/256, 256, 0, stream>>>(wqkv, Wq_hi, Wq_lo, DEPTH, D_, 1536);
  k_split_t<<<(DEPTH*D_*D_+255)/256, 256, 0, stream>>>(wo, Wo_hi, Wo_lo, DEPTH, D_, D_);
  k_split<<<(KCODE*D_+255)/256, 256, 0, stream>>>(cb, cb_hi, cb_lo, KCODE*D_);
  k_cnorm<<<KCODE, 256, 0, stream>>>(cb, cnorm);

  // ---- encoder ----
  k_tok_init<<<(B_*NTOK*D_)/256, 256, 0, stream>>>(x, pos, tok);
  for (int l = 0; l < DEPTH; ++l){
    k_ln_split<<<M_, 256, 0, stream>>>(tok, xn_hi, xn_lo, ln_g + l*D_, ln_b + l*D_);
    k_gemm_split<<<dim3(M_/64, 1536/64), 256, 0, stream>>>(
        xn_hi, xn_lo, Wq_hi + (size_t)l*1536*D_, Wq_lo + (size_t)l*1536*D_,
        qkv, nullptr, nullptr, M_, 1536, D_);
    k_attn2<<<dim3(HEADS, B_), 256, 0, stream>>>(qkv, at_hi, at_lo);
    k_gemm_split<<<dim3(M_/64, D_/64), 256, 0, stream>>>(
        at_hi, at_lo, Wo_hi + (size_t)l*D_*D_, Wo_lo + (size_t)l*D_*D_,
        tok, bo + l*D_, tok, M_, D_, D_);
  }

  // ---- VQ ----
  k_split<<<(M_*D_+255)/256, 256, 0, stream>>>(tok, tok_hi, tok_lo, M_*D_);
  k_gemm_split<<<dim3(M_/64, KCODE/64), 256, 0, stream>>>(
      tok_hi, tok_lo, cb_hi, cb_lo, d2, nullptr, nullptr, M_, KCODE, D_);
  k_argmin<<<M_, 256, 0, stream>>>(d2, cnorm, idx);
  k_gather_nhwc<<<(B_*NTOK*D_)/256, 256, 0, stream>>>(cb, idx, y0);

  // ---- decoder stage 0: 16x16 -> 32x32, Ctot=512 ----
  k_upw<<<(512*256*4+255)/256, 256, 0, stream>>>(up_w0, Wt4, 512, 256);
  k_upconv_nhwc<<<dim3(256/64, 256/64, B_), 256, 0, stream>>>(y0, Wt4, up_b0, cc0, 512, 256, 16, 16, 512);
  k_feat2cc<<<dim3(1024/32, 256/32, B_), dim3(32,8), 0, stream>>>(feat2, cc0, 256, 256, 512, 1024);
  run_conv(cc0, cw0a, W9, va0, 512, 256, 32, 32, stream);
  run_bn(va0, xa0, bnp, bnsc, bnsh, g0a, b0a, 256, 1024, stream);
  run_conv(xa0, cw0b, W9, vb0, 256, 256, 32, 32, stream);
  run_bn(vb0, xb0, bnp, bnsc, bnsh, g0b, b0b, 256, 1024, stream);

  // ---- decoder stage 1: 32x32 -> 64x64, Ctot=256 ----
  k_upw<<<(256*128*4+255)/256, 256, 0, stream>>>(up_w1, Wt4, 256, 128);
  k_upconv_nhwc<<<dim3(1024/64, 128/64, B_), 256, 0, stream>>>(xb0, Wt4, up_b1, cc1, 256, 128, 32, 32, 256);
  k_feat2cc<<<dim3(4096/32, 128/32, B_), dim3(32,8), 0, stream>>>(feat1, cc1, 128, 128, 256, 4096);
  run_conv(cc1, cw1a, W9, va1, 256, 128, 64, 64, stream);
  run_bn(va1, xa1, bnp, bnsc, bnsh, g1a, b1a, 128, 4096, stream);
  run_conv(xa1, cw1b, W9, vb1, 128, 128, 64, 64, stream);
  run_bn(vb1, xb1, bnp, bnsc, bnsh, g1b, b1b, 128, 4096, stream);

  // ---- decoder stage 2: 64x64 -> 128x128, Ctot=128 ----
  k_upw<<<(128*64*4+255)/256, 256, 0, stream>>>(up_w2, Wt4, 128, 64);
  k_upconv_nhwc<<<dim3(4096/64, 64/64, B_), 256, 0, stream>>>(xb1, Wt4, up_b2, cc2, 128, 64, 64, 64, 128);
  k_feat2cc<<<dim3(16384/32, 64/32, B_), dim3(32,8), 0, stream>>>(feat0, cc2, 64, 64, 128, 16384);
  run_conv(cc2, cw2a, W9, va2, 128, 64, 128, 128, stream);
  run_bn(va2, xa2, bnp, bnsc, bnsh, g2a, b2a, 64, 16384, stream);
  run_conv(xa2, cw2b, W9, vb2, 64, 64, 128, 128, stream);
  run_bn(vb2, xb2, bnp, bnsc, bnsh, g2b, b2b, 64, 16384, stream);

  // ---- head ----
  k_last_nhwc<<<(B_*16384)/256, 256, 0, stream>>>(xb2, lw, lb, (float*)d_out);
}

// Round 8
// 3195.817 us; speedup vs baseline: 1.2862x; 1.0045x over previous
//
#include <hip/hip_runtime.h>

#define B_    16
#define NTOK  256
#define D_    512
#define HEADS 16
#define DH    32
#define DEPTH 12
#define KCODE 2048
#define M_    (B_*NTOK)   // 4096 token rows
#define BN_S  512         // BN partial blocks

typedef __attribute__((ext_vector_type(8))) short short8;     // 8 bf16 (4 VGPRs)
typedef __attribute__((ext_vector_type(4))) float float4v;
typedef __attribute__((ext_vector_type(4))) unsigned int uint4v;
typedef __attribute__((ext_vector_type(2))) unsigned int uint2v;
typedef unsigned short ushort;

__device__ __forceinline__ ushort f2b(float f){   // fp32 -> bf16 RNE
  union { float f; unsigned u; } v; v.f = f;
  unsigned r = v.u + 0x7FFFu + ((v.u >> 16) & 1u);
  return (ushort)(r >> 16);
}
__device__ __forceinline__ float b2f(ushort h){
  union { unsigned u; float f; } v; v.u = ((unsigned)h) << 16; return v.f;
}
__device__ __forceinline__ float bits2f(unsigned u){
  union { unsigned u; float f; } v; v.u = u; return v.f;
}

// ---------------- prep kernels ----------------

__global__ void k_tok_init(const float* __restrict__ x, const float* __restrict__ pos,
                           float* __restrict__ tok){
  int i = blockIdx.x*256 + threadIdx.x;
  if (i >= B_*NTOK*D_) return;
  int d = i % D_; int r = i / D_; int t = r % NTOK; int b = r / NTOK;
  tok[i] = x[(b*D_ + d)*NTOK + t] + pos[t*D_ + d];
}

__global__ void k_split(const float* __restrict__ src, ushort* __restrict__ oh,
                        ushort* __restrict__ ol, int n){
  int i = blockIdx.x*256 + threadIdx.x;
  if (i >= n) return;
  float v = src[i];
  ushort h = f2b(v);
  oh[i] = h; ol[i] = f2b(v - b2f(h));
}

// split + transpose: src [L][K][N] f32 -> dst hi/lo [L][N][K] bf16
__global__ void k_split_t(const float* __restrict__ src, ushort* __restrict__ oh,
                          ushort* __restrict__ ol, int L, int K, int N){
  int i = blockIdx.x*256 + threadIdx.x;
  if (i >= L*K*N) return;
  int KN = K*N;
  int l = i / KN; int r = i - l*KN;
  int k = r / N;  int n = r - k*N;
  float v = src[i];
  ushort h = f2b(v);
  size_t o = (size_t)l*KN + (size_t)n*K + k;
  oh[o] = h; ol[o] = f2b(v - b2f(h));
}

// conv weights: [Cout][Cin][3][3] f32 -> W9 [9tap][Cout][Cin] bf16
__global__ void k_w9(const float* __restrict__ w, ushort* __restrict__ W9,
                     int Cin, int Cout){
  int i = blockIdx.x*256 + threadIdx.x;
  if (i >= Cout*Cin*9) return;
  int co = i / (Cin*9); int r = i - co*(Cin*9);
  int ci = r / 9; int tap = r - ci*9;
  W9[((size_t)tap*Cout + co)*Cin + ci] = f2b(w[i]);
}

// upconv weights: [Cin][Cout][2][2] f32 -> Wt4 [tap][Cout][Cin] bf16
__global__ void k_upw(const float* __restrict__ w, ushort* __restrict__ Wt4,
                      int Cin, int Cout){
  int i = blockIdx.x*256 + threadIdx.x;
  if (i >= Cin*Cout*4) return;
  int ci = i / (Cout*4); int r = i - ci*(Cout*4);
  int co = r >> 2; int tap = r & 3;
  Wt4[((size_t)tap*Cout + co)*Cin + ci] = f2b(w[i]);
}

// LayerNorm fused with bf16 hi/lo split
__global__ void k_ln_split(const float* __restrict__ in, ushort* __restrict__ oh,
                           ushort* __restrict__ ol, const float* __restrict__ g,
                           const float* __restrict__ bta){
  int row = blockIdx.x; int t = threadIdx.x;
  const float* xr = in + (size_t)row*D_;
  float x0 = xr[t], x1 = xr[t+256];
  __shared__ float r1[256], r2[256];
  r1[t] = x0+x1; r2[t] = x0*x0 + x1*x1;
  __syncthreads();
  for (int off=128; off>0; off>>=1){
    if (t<off){ r1[t]+=r1[t+off]; r2[t]+=r2[t+off]; }
    __syncthreads();
  }
  float mean = r1[0] * (1.f/D_);
  float var  = r2[0] * (1.f/D_) - mean*mean;
  float inv  = rsqrtf(var + 1e-5f);
  float y0 = (x0-mean)*inv*g[t]     + bta[t];
  float y1 = (x1-mean)*inv*g[t+256] + bta[t+256];
  size_t o = (size_t)row*D_;
  ushort h0 = f2b(y0), h1 = f2b(y1);
  oh[o+t] = h0;     ol[o+t]     = f2b(y0 - b2f(h0));
  oh[o+t+256] = h1; ol[o+t+256] = f2b(y1 - b2f(h1));
}

// ---------------- split-bf16 MFMA GEMM (3-term, fp32-accurate) ----------------
__global__ __launch_bounds__(256) void k_gemm_split(
    const ushort* __restrict__ Ah, const ushort* __restrict__ Al,
    const ushort* __restrict__ Bh, const ushort* __restrict__ Bl,
    float* __restrict__ C, const float* __restrict__ bias,
    const float* __restrict__ resid, int M, int N, int K){
  __shared__ ushort Ash[64][40], Asl[64][40], Bsh[64][40], Bsl[64][40];
  const int tid = threadIdx.x;
  const int m_base = blockIdx.x*64, n_base = blockIdx.y*64;
  const int lane = tid & 63, wv = tid >> 6;
  const int quad = lane >> 4, r16 = lane & 15;
  const int m_off = (wv & 1)*32, n_off = (wv >> 1)*32;
  const int srow = tid & 63, skq = tid >> 6;
  const size_t arow = (size_t)(m_base + srow)*K + skq*8;
  const size_t brow = (size_t)(n_base + srow)*K + skq*8;
  float4v acc00={}, acc01={}, acc10={}, acc11={};
  for (int k0 = 0; k0 < K; k0 += 32){
    *(uint4v*)&Ash[srow][skq*8] = *(const uint4v*)(Ah + arow + k0);
    *(uint4v*)&Asl[srow][skq*8] = *(const uint4v*)(Al + arow + k0);
    *(uint4v*)&Bsh[srow][skq*8] = *(const uint4v*)(Bh + brow + k0);
    *(uint4v*)&Bsl[srow][skq*8] = *(const uint4v*)(Bl + brow + k0);
    __syncthreads();
    short8 afh0 = *(const short8*)&Ash[m_off      + r16][quad*8];
    short8 afh1 = *(const short8*)&Ash[m_off + 16 + r16][quad*8];
    short8 afl0 = *(const short8*)&Asl[m_off      + r16][quad*8];
    short8 afl1 = *(const short8*)&Asl[m_off + 16 + r16][quad*8];
    short8 bfh0 = *(const short8*)&Bsh[n_off      + r16][quad*8];
    short8 bfh1 = *(const short8*)&Bsh[n_off + 16 + r16][quad*8];
    short8 bfl0 = *(const short8*)&Bsl[n_off      + r16][quad*8];
    short8 bfl1 = *(const short8*)&Bsl[n_off + 16 + r16][quad*8];
    acc00 = __builtin_amdgcn_mfma_f32_16x16x32_bf16(bfh0, afh0, acc00, 0,0,0);
    acc00 = __builtin_amdgcn_mfma_f32_16x16x32_bf16(bfh0, afl0, acc00, 0,0,0);
    acc00 = __builtin_amdgcn_mfma_f32_16x16x32_bf16(bfl0, afh0, acc00, 0,0,0);
    acc01 = __builtin_amdgcn_mfma_f32_16x16x32_bf16(bfh1, afh0, acc01, 0,0,0);
    acc01 = __builtin_amdgcn_mfma_f32_16x16x32_bf16(bfh1, afl0, acc01, 0,0,0);
    acc01 = __builtin_amdgcn_mfma_f32_16x16x32_bf16(bfl1, afh0, acc01, 0,0,0);
    acc10 = __builtin_amdgcn_mfma_f32_16x16x32_bf16(bfh0, afh1, acc10, 0,0,0);
    acc10 = __builtin_amdgcn_mfma_f32_16x16x32_bf16(bfh0, afl1, acc10, 0,0,0);
    acc10 = __builtin_amdgcn_mfma_f32_16x16x32_bf16(bfl0, afh1, acc10, 0,0,0);
    acc11 = __builtin_amdgcn_mfma_f32_16x16x32_bf16(bfh1, afh1, acc11, 0,0,0);
    acc11 = __builtin_amdgcn_mfma_f32_16x16x32_bf16(bfh1, afl1, acc11, 0,0,0);
    acc11 = __builtin_amdgcn_mfma_f32_16x16x32_bf16(bfl1, afh1, acc11, 0,0,0);
    __syncthreads();
  }
  int m0 = m_base + m_off + r16;
  int n0 = n_base + n_off + quad*4;
  float4v bv0 = {}, bv1 = {};
  if (bias){ bv0 = *(const float4v*)(bias + n0); bv1 = *(const float4v*)(bias + n0 + 16); }
  float4v v00 = acc00 + bv0, v01 = acc01 + bv1, v10 = acc10 + bv0, v11 = acc11 + bv1;
  if (resid){
    v00 += *(const float4v*)(resid + (size_t)m0*N + n0);
    v01 += *(const float4v*)(resid + (size_t)m0*N + n0 + 16);
    v10 += *(const float4v*)(resid + (size_t)(m0+16)*N + n0);
    v11 += *(const float4v*)(resid + (size_t)(m0+16)*N + n0 + 16);
  }
  *(float4v*)(C + (size_t)m0*N + n0)          = v00;
  *(float4v*)(C + (size_t)m0*N + n0 + 16)     = v01;
  *(float4v*)(C + (size_t)(m0+16)*N + n0)     = v10;
  *(float4v*)(C + (size_t)(m0+16)*N + n0 + 16)= v11;
}

// ---------------- attention: one block per (b,h), K/V in LDS ----------------
__global__ __launch_bounds__(256) void k_attn2(const float* __restrict__ qkv,
                                               ushort* __restrict__ oh,
                                               ushort* __restrict__ ol){
  __shared__ float4v ks[NTOK*8];
  __shared__ float4v vs[NTOK*8];
  const int h = blockIdx.x, b = blockIdx.y, t = threadIdx.x;
  const float* base = qkv + (size_t)b*NTOK*1536;
  const int koff = 512 + h*DH, voff = 1024 + h*DH;
  for (int i = t; i < NTOK*8; i += 256){
    int j = i >> 3, d4 = i & 7;
    ks[i] = *(const float4v*)(base + (size_t)j*1536 + koff + d4*4);
    vs[i] = *(const float4v*)(base + (size_t)j*1536 + voff + d4*4);
  }
  float4v q8[8];
  const float* qrow = base + (size_t)t*1536 + h*DH;
  #pragma unroll
  for (int d4 = 0; d4 < 8; ++d4) q8[d4] = *(const float4v*)(qrow + d4*4);
  __syncthreads();
  float4v o8[8];
  #pragma unroll
  for (int d4 = 0; d4 < 8; ++d4) o8[d4] = float4v{0.f,0.f,0.f,0.f};
  float l = 0.f;
  for (int j = 0; j < NTOK; ++j){
    float s = 0.f;
    #pragma unroll
    for (int d4 = 0; d4 < 8; ++d4){
      float4v kk = ks[j*8 + d4];
      s += q8[d4].x*kk.x + q8[d4].y*kk.y + q8[d4].z*kk.z + q8[d4].w*kk.w;
    }
    float e = __expf(s * 0.17677669529663689f);
    l += e;
    #pragma unroll
    for (int d4 = 0; d4 < 8; ++d4){
      float4v vv = vs[j*8 + d4];
      o8[d4].x += e*vv.x; o8[d4].y += e*vv.y; o8[d4].z += e*vv.z; o8[d4].w += e*vv.w;
    }
  }
  float inv = 1.f / l;
  size_t ob = (size_t)(b*NTOK + t)*D_ + h*DH;
  #pragma unroll
  for (int d4 = 0; d4 < 8; ++d4){
    float vals[4] = {o8[d4].x*inv, o8[d4].y*inv, o8[d4].z*inv, o8[d4].w*inv};
    #pragma unroll
    for (int r = 0; r < 4; ++r){
      ushort hh = f2b(vals[r]);
      oh[ob + d4*4 + r] = hh;
      ol[ob + d4*4 + r] = f2b(vals[r] - b2f(hh));
    }
  }
}

// ---------------- VQ ----------------
__global__ void k_cnorm(const float* __restrict__ cb, float* __restrict__ cnorm){
  int k = blockIdx.x, t = threadIdx.x;
  float v1 = cb[(size_t)k*D_ + t];
  float v2 = cb[(size_t)k*D_ + t + 256];
  __shared__ float r[256];
  r[t] = v1*v1 + v2*v2;
  __syncthreads();
  for (int off=128; off>0; off>>=1){
    if (t<off) r[t]+=r[t+off];
    __syncthreads();
  }
  if (t==0) cnorm[k] = r[0];
}

__global__ void k_argmin(const float* __restrict__ d2, const float* __restrict__ cnorm,
                         int* __restrict__ idx){
  int m = blockIdx.x, t = threadIdx.x;
  float best = 3.4e38f; int bk = 0;
  for (int k = t; k < KCODE; k += 256){
    float s = cnorm[k] - 2.f*d2[(size_t)m*KCODE + k];
    if (s < best){ best = s; bk = k; }
  }
  __shared__ float bs[256]; __shared__ int bi[256];
  bs[t]=best; bi[t]=bk;
  __syncthreads();
  for (int off=128; off>0; off>>=1){
    if (t<off){
      if (bs[t+off] < bs[t] || (bs[t+off]==bs[t] && bi[t+off]<bi[t])){
        bs[t]=bs[t+off]; bi[t]=bi[t+off];
      }
    }
    __syncthreads();
  }
  if (t==0) idx[m] = bi[0];
}

// y0 NHWC bf16: y0[b][t][d] = codebook[idx[b,t]][d]
__global__ void k_gather_nhwc(const float* __restrict__ cb, const int* __restrict__ idx,
                              ushort* __restrict__ y0){
  int i = blockIdx.x*256 + threadIdx.x;
  if (i >= B_*NTOK*D_) return;
  int d = i % D_; int r = i / D_; int t = r % NTOK; int b = r / NTOK;
  y0[i] = f2b(cb[(size_t)idx[b*NTOK + t]*D_ + d]);
}

// ---------------- decoder (NHWC bf16) ----------------

// 3x3 conv pad1, patch-staged implicit GEMM.
// 8x8 pixel tile -> 10x10 patch in LDS once per 32-ch K-chunk; 9 taps x 4 MFMA
// per barrier pair; weight fragments loaded direct from global (L2-resident).
// grid ((H/8)*(W/8), Cout/64, B_).
__global__ __launch_bounds__(256) void k_conv_nhwc(
    const ushort* __restrict__ X, const ushort* __restrict__ W9,
    float* __restrict__ Y, int Cin, int Cout, int H, int W){
  __shared__ ushort Xs[128][38];      // 10x10 patch rows x 32ch, stride 19 dwords
  const int HW = H*W;
  const int tid = threadIdx.x;
  const int b = blockIdx.z;
  const int tiles_w = W >> 3;
  const int th0 = (blockIdx.x / tiles_w) * 8;
  const int tw0 = (blockIdx.x - (blockIdx.x / tiles_w)*tiles_w) * 8;
  const int n_base = blockIdx.y*64;
  const int lane = tid & 63, wv = tid >> 6;
  const int quad = lane >> 4, r16 = lane & 15;
  const int m_off = (wv & 1)*32, n_off = (wv >> 1)*32;
  const ushort* Xb = X + (size_t)b*HW*Cin;
  // staging precompute: 400 items (100 patch rows x 4 ch-segments), 2/thread
  const ushort* sptr[2]; int srw[2], ssg[2]; bool sok[2];
  #pragma unroll
  for (int e = 0; e < 2; ++e){
    int item = tid + e*256;
    int row = (item >> 2) & 127;
    int seg = item & 3;
    int ph = row / 10, pw = row - ph*10;
    int gh = th0 + ph - 1, gw = tw0 + pw - 1;
    bool ok = (item < 400) && gh >= 0 && gh < H && gw >= 0 && gw < W;
    int pidx = ok ? (gh*W + gw) : 0;
    srw[e] = row; ssg[e] = seg; sok[e] = ok;
    sptr[e] = Xb + ((size_t)pidx*Cin + seg*8);
  }
  const uint4v zz = {};
  float4v a00={}, a01={}, a10={}, a11={};
  const int mA = m_off + r16, mB = mA + 16;
  const int rA0 = ((mA>>3))*10 + (mA&7);    // patch row for tap (0,0)
  const int rB0 = ((mB>>3))*10 + (mB&7);
  for (int k0 = 0; k0 < Cin; k0 += 32){
    if (k0) __syncthreads();
    #pragma unroll
    for (int e = 0; e < 2; ++e){
      uint4v v = sok[e] ? *(const uint4v*)(sptr[e] + k0) : zz;
      *(uint4v*)&Xs[srw[e]][ssg[e]*8] = v;
    }
    __syncthreads();
    #pragma unroll
    for (int tap = 0; tap < 9; ++tap){
      const int kh = tap/3, kw = tap - (tap/3)*3;
      const ushort* wp = W9 + ((size_t)tap*Cout + n_base)*Cin + k0 + quad*8;
      short8 wf0 = *(const short8*)(wp + (size_t)(n_off      + r16)*Cin);
      short8 wf1 = *(const short8*)(wp + (size_t)(n_off + 16 + r16)*Cin);
      short8 xf0 = *(const short8*)&Xs[rA0 + kh*10 + kw][quad*8];
      short8 xf1 = *(const short8*)&Xs[rB0 + kh*10 + kw][quad*8];
      a00 = __builtin_amdgcn_mfma_f32_16x16x32_bf16(wf0, xf0, a00, 0,0,0);
      a01 = __builtin_amdgcn_mfma_f32_16x16x32_bf16(wf0, xf1, a01, 0,0,0);
      a10 = __builtin_amdgcn_mfma_f32_16x16x32_bf16(wf1, xf0, a10, 0,0,0);
      a11 = __builtin_amdgcn_mfma_f32_16x16x32_bf16(wf1, xf1, a11, 0,0,0);
    }
  }
  float* Yb = Y + (size_t)b*HW*Cout;
  int pA = (th0 + (mA>>3))*W + tw0 + (mA&7);
  int pB = (th0 + (mB>>3))*W + tw0 + (mB&7);
  int co0 = n_base + n_off + quad*4, co1 = co0 + 16;
  *(float4v*)(Yb + (size_t)pA*Cout + co0) = a00;
  *(float4v*)(Yb + (size_t)pB*Cout + co0) = a01;
  *(float4v*)(Yb + (size_t)pA*Cout + co1) = a10;
  *(float4v*)(Yb + (size_t)pB*Cout + co1) = a11;
}

// ConvTranspose2d k=2 s=2: X staged once per K-chunk, 4 weight taps share it.
__global__ __launch_bounds__(256) void k_upconv_nhwc(
    const ushort* __restrict__ X, const ushort* __restrict__ Wt4,
    const float* __restrict__ bias, ushort* __restrict__ CC,
    int Cin, int Cout, int Hi, int Wi, int Ctot){
  __shared__ ushort Xs[64][40], Ws[4][64][40];
  const int HWi = Hi*Wi;
  const int tid = threadIdx.x;
  const int b = blockIdx.z;
  const int m_base = blockIdx.x*64;
  const int n_base = blockIdx.y*64;
  const int lane = tid & 63, wv = tid >> 6;
  const int quad = lane >> 4, r16 = lane & 15;
  const int m_off = (wv & 1)*32, n_off = (wv >> 1)*32;
  const int srow = tid & 63, skq = tid >> 6;
  const ushort* xrow = X + ((size_t)b*HWi + m_base + srow)*Cin + skq*8;
  const ushort* w0 = Wt4 + ((size_t)0*Cout + n_base + srow)*Cin + skq*8;
  const ushort* w1 = Wt4 + ((size_t)1*Cout + n_base + srow)*Cin + skq*8;
  const ushort* w2 = Wt4 + ((size_t)2*Cout + n_base + srow)*Cin + skq*8;
  const ushort* w3 = Wt4 + ((size_t)3*Cout + n_base + srow)*Cin + skq*8;
  float4v acc[4][4];
  #pragma unroll
  for (int t = 0; t < 4; ++t)
    #pragma unroll
    for (int q = 0; q < 4; ++q) acc[t][q] = float4v{0.f,0.f,0.f,0.f};
  for (int k0 = 0; k0 < Cin; k0 += 32){
    *(uint4v*)&Xs[srow][skq*8]    = *(const uint4v*)(xrow + k0);
    *(uint4v*)&Ws[0][srow][skq*8] = *(const uint4v*)(w0 + k0);
    *(uint4v*)&Ws[1][srow][skq*8] = *(const uint4v*)(w1 + k0);
    *(uint4v*)&Ws[2][srow][skq*8] = *(const uint4v*)(w2 + k0);
    *(uint4v*)&Ws[3][srow][skq*8] = *(const uint4v*)(w3 + k0);
    __syncthreads();
    short8 xf0 = *(const short8*)&Xs[m_off      + r16][quad*8];
    short8 xf1 = *(const short8*)&Xs[m_off + 16 + r16][quad*8];
    #pragma unroll
    for (int t = 0; t < 4; ++t){
      short8 wf0 = *(const short8*)&Ws[t][n_off      + r16][quad*8];
      short8 wf1 = *(const short8*)&Ws[t][n_off + 16 + r16][quad*8];
      acc[t][0] = __builtin_amdgcn_mfma_f32_16x16x32_bf16(wf0, xf0, acc[t][0], 0,0,0);
      acc[t][1] = __builtin_amdgcn_mfma_f32_16x16x32_bf16(wf0, xf1, acc[t][1], 0,0,0);
      acc[t][2] = __builtin_amdgcn_mfma_f32_16x16x32_bf16(wf1, xf0, acc[t][2], 0,0,0);
      acc[t][3] = __builtin_amdgcn_mfma_f32_16x16x32_bf16(wf1, xf1, acc[t][3], 0,0,0);
    }
    __syncthreads();
  }
  const int Wo = 2*Wi, HWo = 4*HWi;
  int co0 = n_base + n_off + quad*4, co1 = co0 + 16;
  float4v bv0 = *(const float4v*)(bias + co0);
  float4v bv1 = *(const float4v*)(bias + co1);
  int px0 = m_base + m_off + r16, px1 = px0 + 16;
  #pragma unroll
  for (int j = 0; j < 2; ++j){
    int p = j ? px1 : px0;
    int r = p / Wi, c = p - r*Wi;
    #pragma unroll
    for (int t = 0; t < 4; ++t){
      int opix = (2*r + (t>>1))*Wo + 2*c + (t&1);
      ushort* o = CC + ((size_t)b*HWo + opix)*Ctot;
      float4v vA = acc[t][0 + j] + bv0;
      float4v vB = acc[t][2 + j] + bv1;
      uint2v pA, pB;
      pA.x = (unsigned)f2b(vA.x) | ((unsigned)f2b(vA.y) << 16);
      pA.y = (unsigned)f2b(vA.z) | ((unsigned)f2b(vA.w) << 16);
      pB.x = (unsigned)f2b(vB.x) | ((unsigned)f2b(vB.y) << 16);
      pB.y = (unsigned)f2b(vB.z) | ((unsigned)f2b(vB.w) << 16);
      *(uint2v*)(o + co0) = pA;
      *(uint2v*)(o + co1) = pB;
    }
  }
}

// NCHW fp32 skip feature -> NHWC bf16 concat channels [Coff, Coff+Cf)
__global__ void k_feat2cc(const float* __restrict__ feat, ushort* __restrict__ cc,
                          int Cf, int Coff, int Ctot, int HW){
  __shared__ ushort t[32][33];
  int pb = blockIdx.x*32, cbs = blockIdx.y*32, b = blockIdx.z;
  int tx = threadIdx.x, ty = threadIdx.y;
  #pragma unroll
  for (int i = 0; i < 4; ++i){
    int c = cbs + ty + i*8;
    t[ty + i*8][tx] = f2b(feat[((size_t)(b*Cf) + c)*HW + pb + tx]);
  }
  __syncthreads();
  #pragma unroll
  for (int i = 0; i < 4; ++i){
    int p = pb + ty + i*8;
    cc[((size_t)b*HW + p)*Ctot + Coff + cbs + tx] = t[tx][ty + i*8];
  }
}

// BN stats phase 1: BN_S blocks, float4 channel-quads, LDS cross-group reduce.
__global__ __launch_bounds__(256) void k_bnstats_nhwc(
    const float* __restrict__ x, float* __restrict__ part, int C, int HW){
  const int s = blockIdx.x, tid = threadIdx.x;
  const int R = B_*HW;
  const int chunk = R / BN_S;
  const int L = C >> 2;
  const int G = 256 / L;
  const int c4 = tid % L, g = tid / L;
  float4v a = {}, q = {};
  const float* xb = x + (size_t)(s*chunk)*C + 4*c4;
  for (int r = g; r < chunk; r += G){
    float4v v = *(const float4v*)(xb + (size_t)r*C);
    a += v; q += v*v;
  }
  __shared__ float4v h1[256], h2[256];
  h1[tid] = a; h2[tid] = q;
  __syncthreads();
  if (tid < L){
    float4v ra = h1[tid], rq = h2[tid];
    for (int gg = 1; gg < G; ++gg){ ra += h1[tid + gg*L]; rq += h2[tid + gg*L]; }
    int c0 = 4*c4;
    part[(size_t)(c0+0)*BN_S + s] = ra.x;
    part[(size_t)(c0+1)*BN_S + s] = ra.y;
    part[(size_t)(c0+2)*BN_S + s] = ra.z;
    part[(size_t)(c0+3)*BN_S + s] = ra.w;
    part[(size_t)(C+c0+0)*BN_S + s] = rq.x;
    part[(size_t)(C+c0+1)*BN_S + s] = rq.y;
    part[(size_t)(C+c0+2)*BN_S + s] = rq.z;
    part[(size_t)(C+c0+3)*BN_S + s] = rq.w;
  }
}

// BN finalize: one block per channel reduces BN_S partials -> scale/shift
__global__ void k_bnfinal(const float* __restrict__ part, const float* __restrict__ g,
                          const float* __restrict__ bb, float* __restrict__ scale,
                          float* __restrict__ shift, int C, int cnt){
  int c = blockIdx.x, t = threadIdx.x;  // 256 threads
  __shared__ float r1[256], r2[256];
  r1[t] = part[(size_t)c*BN_S + t]       + part[(size_t)c*BN_S + t + 256];
  r2[t] = part[(size_t)(C + c)*BN_S + t] + part[(size_t)(C + c)*BN_S + t + 256];
  __syncthreads();
  for (int off = 128; off > 0; off >>= 1){
    if (t < off){ r1[t] += r1[t+off]; r2[t] += r2[t+off]; }
    __syncthreads();
  }
  if (t == 0){
    float m = r1[0]/cnt;
    float v = r2[0]/cnt - m*m;
    float sc = g[c]*rsqrtf(v + 1e-5f);
    scale[c] = sc;
    shift[c] = bb[c] - m*sc;
  }
}

// BN apply + ReLU, fp32 NHWC -> bf16 NHWC
__global__ void k_bnapply_nhwc(const float* __restrict__ x, ushort* __restrict__ y,
                               const float* __restrict__ scale,
                               const float* __restrict__ shift, int C, int n4){
  int i = blockIdx.x*256 + threadIdx.x;
  if (i >= n4) return;
  float4v v = *(const float4v*)(x + (size_t)4*i);
  int c0 = (4*i) % C;
  float4v sc = *(const float4v*)(scale + c0);
  float4v sh = *(const float4v*)(shift + c0);
  float r0 = fmaxf(v.x*sc.x + sh.x, 0.f);
  float r1 = fmaxf(v.y*sc.y + sh.y, 0.f);
  float r2 = fmaxf(v.z*sc.z + sh.z, 0.f);
  float r3 = fmaxf(v.w*sc.w + sh.w, 0.f);
  uint2v pk;
  pk.x = (unsigned)f2b(r0) | ((unsigned)f2b(r1) << 16);
  pk.y = (unsigned)f2b(r2) | ((unsigned)f2b(r3) << 16);
  *(uint2v*)(y + (size_t)4*i) = pk;
}

// final 1x1 conv (64ch NHWC bf16 -> 1) + sigmoid
__global__ void k_last_nhwc(const ushort* __restrict__ x, const float* __restrict__ lw,
                            const float* __restrict__ lb, float* __restrict__ out){
  __shared__ float wsm[64];
  int tid = threadIdx.x;
  if (tid < 64) wsm[tid] = lw[tid];
  __syncthreads();
  int i = blockIdx.x*256 + tid;
  const uint4v* xr = (const uint4v*)(x + (size_t)i*64);
  float acc = lb[0];
  #pragma unroll
  for (int q = 0; q < 8; ++q){
    uint4v u = xr[q];
    unsigned uu[4] = {u.x, u.y, u.z, u.w};
    #pragma unroll
    for (int k = 0; k < 4; ++k){
      acc += bits2f(uu[k] << 16)          * wsm[q*8 + 2*k];
      acc += bits2f(uu[k] & 0xffff0000u)  * wsm[q*8 + 2*k + 1];
    }
  }
  out[i] = 1.f/(1.f + __expf(-acc));
}

// ---------------- host ----------------
#define MBx 1048576ull

static inline void run_conv(const ushort* in, const float* w, ushort* W9,
                            float* out, int Cin, int Cout, int H, int W,
                            hipStream_t stream){
  int total = Cout*Cin*9;
  k_w9<<<(total+255)/256, 256, 0, stream>>>(w, W9, Cin, Cout);
  k_conv_nhwc<<<dim3((H>>3)*(W>>3), Cout/64, B_), 256, 0, stream>>>(in, W9, out, Cin, Cout, H, W);
}

static inline void run_bn(const float* x, ushort* y, float* part, float* scale, float* shift,
                          const float* g, const float* bb, int C, int HW, hipStream_t stream){
  k_bnstats_nhwc<<<BN_S, 256, 0, stream>>>(x, part, C, HW);
  k_bnfinal<<<C, 256, 0, stream>>>(part, g, bb, scale, shift, C, B_*HW);
  int n4 = B_*HW*C/4;
  k_bnapply_nhwc<<<(n4+255)/256, 256, 0, stream>>>(x, y, scale, shift, C, n4);
}

extern "C" void kernel_launch(void* const* d_in, const int* in_sizes, int n_in,
                              void* d_out, int out_size, void* d_ws, size_t ws_size,
                              hipStream_t stream){
  const float* x     = (const float*)d_in[0];
  const float* feat0 = (const float*)d_in[1];
  const float* feat1 = (const float*)d_in[2];
  const float* feat2 = (const float*)d_in[3];
  const float* pos   = (const float*)d_in[4];
  const float* cb    = (const float*)d_in[5];
  const float* ln_g  = (const float*)d_in[6];
  const float* ln_b  = (const float*)d_in[7];
  const float* wqkv  = (const float*)d_in[8];
  const float* wo    = (const float*)d_in[9];
  const float* bo    = (const float*)d_in[10];
  const float* up_w0 = (const float*)d_in[11];
  const float* up_b0 = (const float*)d_in[12];
  const float* cw0a  = (const float*)d_in[13];
  const float* g0a   = (const float*)d_in[14];
  const float* b0a   = (const float*)d_in[15];
  const float* cw0b  = (const float*)d_in[16];
  const float* g0b   = (const float*)d_in[17];
  const float* b0b   = (const float*)d_in[18];
  const float* up_w1 = (const float*)d_in[19];
  const float* up_b1 = (const float*)d_in[20];
  const float* cw1a  = (const float*)d_in[21];
  const float* g1a   = (const float*)d_in[22];
  const float* b1a   = (const float*)d_in[23];
  const float* cw1b  = (const float*)d_in[24];
  const float* g1b   = (const float*)d_in[25];
  const float* b1b   = (const float*)d_in[26];
  const float* up_w2 = (const float*)d_in[27];
  const float* up_b2 = (const float*)d_in[28];
  const float* cw2a  = (const float*)d_in[29];
  const float* g2a   = (const float*)d_in[30];
  const float* b2a   = (const float*)d_in[31];
  const float* cw2b  = (const float*)d_in[32];
  const float* g2b   = (const float*)d_in[33];
  const float* b2b   = (const float*)d_in[34];
  const float* lw    = (const float*)d_in[35];
  const float* lb    = (const float*)d_in[36];

  char* ws = (char*)d_ws;
  // encoder/VQ scratch (region 0..134MB)
  float*  tok     = (float*) (ws);
  ushort* xn_hi   = (ushort*)(ws +  8388608ull);
  ushort* xn_lo   = (ushort*)(ws + 12582912ull);
  float*  qkv     = (float*) (ws + 16777216ull);
  ushort* at_hi   = (ushort*)(ws + 41943040ull);
  ushort* at_lo   = (ushort*)(ws + 46137344ull);
  ushort* tok_hi  = (ushort*)(ws + 50331648ull);
  ushort* tok_lo  = (ushort*)(ws + 54525952ull);
  ushort* Wq_hi   = (ushort*)(ws + 58720256ull);
  ushort* Wq_lo   = (ushort*)(ws + 77594624ull);
  ushort* Wo_hi   = (ushort*)(ws + 96468992ull);
  ushort* Wo_lo   = (ushort*)(ws + 102760448ull);
  ushort* cb_hi   = (ushort*)(ws + 109051904ull);
  ushort* cb_lo   = (ushort*)(ws + 111149056ull);
  float*  cnorm   = (float*) (ws + 113246208ull);
  int*    idx     = (int*)   (ws + 113254400ull);
  float*  d2      = (float*) (ws + 58720256ull);   // overlaps Wq (dead at VQ time)
  // tail: weights + bn scratch + y0
  ushort* W9   = (ushort*)(ws + 134*MBx);          // 2.25 MB max
  float* bnsc  = (float*) (ws + 136*MBx + 524288); // 1 KB
  float* bnsh  = (float*) (ws + 136*MBx + 528384); // 1 KB
  ushort* Wt4  = (ushort*)(ws + 137*MBx);          // 1 MB max
  float* bnp   = (float*) (ws + 138*MBx);          // 1 MB max
  ushort* y0   = (ushort*)(ws + 139*MBx);
  // decoder ping-pong
  ushort* cc0 = (ushort*)(ws + 146*MBx);
  float*  va0 = (float*) (ws + 163*MBx);
  ushort* xa0 = (ushort*)(ws + 180*MBx);
  float*  vb0 = (float*) (ws + 146*MBx);
  ushort* xb0 = (ushort*)(ws + 189*MBx);
  ushort* cc1 = (ushort*)(ws + 0*MBx);
  float*  va1 = (float*) (ws + 34*MBx);
  ushort* xa1 = (ushort*)(ws + 68*MBx);
  float*  vb1 = (float*) (ws + 85*MBx);
  ushort* xb1 = (ushort*)(ws + 146*MBx);
  ushort* cc2 = (ushort*)(ws + 0*MBx);
  float*  va2 = (float*) (ws + 67*MBx);
  ushort* xa2 = (ushort*)(ws + 146*MBx);
  float*  vb2 = (float*) (ws + 0*MBx);
  ushort* xb2 = (ushort*)(ws + 67*MBx);

  // ---- weight prep ----
  k_split_t<<<(DEPTH*D_*1536+255)/256, 256, 0, stream>>>(wqkv, Wq_hi, Wq_lo, DEPTH, D_, 1536);
  k_split_t<<<(DEPTH*D_*D_+255)/256, 256, 0, stream>>>(wo, Wo_hi, Wo_lo, DEPTH, D_, D_);
  k_split<<<(KCODE*D_+255)/256, 256, 0, stream>>>(cb, cb_hi, cb_lo, KCODE*D_);
  k_cnorm<<<KCODE, 256, 0, stream>>>(cb, cnorm);

  // ---- encoder ----
  k_tok_init<<<(B_*NTOK*D_)/256, 256, 0, stream>>>(x, pos, tok);
  for (int l = 0; l < DEPTH; ++l){
    k_ln_split<<<M_, 256, 0, stream>>>(tok, xn_hi, xn_lo, ln_g + l*D_, ln_b + l*D_);
    k_gemm_split<<<dim3(M_/64, 1536/64), 256, 0, stream>>>(
        xn_hi, xn_lo, Wq_hi + (size_t)l*1536*D_, Wq_lo + (size_t)l*1536*D_,
        qkv, nullptr, nullptr, M_, 1536, D_);
    k_attn2<<<dim3(HEADS, B_), 256, 0, stream>>>(qkv, at_hi, at_lo);
    k_gemm_split<<<dim3(M_/64, D_/64), 256, 0, stream>>>(
        at_hi, at_lo, Wo_hi + (size_t)l*D_*D_, Wo_lo + (size_t)l*D_*D_,
        tok, bo + l*D_, tok, M_, D_, D_);
  }

  // ---- VQ ----
  k_split<<<(M_*D_+255)/256, 256, 0, stream>>>(tok, tok_hi, tok_lo, M_*D_);
  k_gemm_split<<<dim3(M_/64, KCODE/64), 256, 0, stream>>>(
      tok_hi, tok_lo, cb_hi, cb_lo, d2, nullptr, nullptr, M_, KCODE, D_);
  k_argmin<<<M_, 256, 0, stream>>>(d2, cnorm, idx);
  k_gather_nhwc<<<(B_*NTOK*D_)/256, 256, 0, stream>>>(cb, idx, y0);

  // ---- decoder stage 0: 16x16 -> 32x32, Ctot=512 ----
  k_upw<<<(512*256*4+255)/256, 256, 0, stream>>>(up_w0, Wt4, 512, 256);
  k_upconv_nhwc<<<dim3(256/64, 256/64, B_), 256, 0, stream>>>(y0, Wt4, up_b0, cc0, 512, 256, 16, 16, 512);
  k_feat2cc<<<dim3(1024/32, 256/32, B_), dim3(32,8), 0, stream>>>(feat2, cc0, 256, 256, 512, 1024);
  run_conv(cc0, cw0a, W9, va0, 512, 256, 32, 32, stream);
  run_bn(va0, xa0, bnp, bnsc, bnsh, g0a, b0a, 256, 1024, stream);
  run_conv(xa0, cw0b, W9, vb0, 256, 256, 32, 32, stream);
  run_bn(vb0, xb0, bnp, bnsc, bnsh, g0b, b0b, 256, 1024, stream);

  // ---- decoder stage 1: 32x32 -> 64x64, Ctot=256 ----
  k_upw<<<(256*128*4+255)/256, 256, 0, stream>>>(up_w1, Wt4, 256, 128);
  k_upconv_nhwc<<<dim3(1024/64, 128/64, B_), 256, 0, stream>>>(xb0, Wt4, up_b1, cc1, 256, 128, 32, 32, 256);
  k_feat2cc<<<dim3(4096/32, 128/32, B_), dim3(32,8), 0, stream>>>(feat1, cc1, 128, 128, 256, 4096);
  run_conv(cc1, cw1a, W9, va1, 256, 128, 64, 64, stream);
  run_bn(va1, xa1, bnp, bnsc, bnsh, g1a, b1a, 128, 4096, stream);
  run_conv(xa1, cw1b, W9, vb1, 128, 128, 64, 64, stream);
  run_bn(vb1, xb1, bnp, bnsc, bnsh, g1b, b1b, 128, 4096, stream);

  // ---- decoder stage 2: 64x64 -> 128x128, Ctot=128 ----
  k_upw<<<(128*64*4+255)/256, 256, 0, stream>>>(up_w2, Wt4, 128, 64);
  k_upconv_nhwc<<<dim3(4096/64, 64/64, B_), 256, 0, stream>>>(xb1, Wt4, up_b2, cc2, 128, 64, 64, 64, 128);
  k_feat2cc<<<dim3(16384/32, 64/32, B_), dim3(32,8), 0, stream>>>(feat0, cc2, 64, 64, 128, 16384);
  run_conv(cc2, cw2a, W9, va2, 128, 64, 128, 128, stream);
  run_bn(va2, xa2, bnp, bnsc, bnsh, g2a, b2a, 64, 16384, stream);
  run_conv(xa2, cw2b, W9, vb2, 64, 64, 128, 128, stream);
  run_bn(vb2, xb2, bnp, bnsc, bnsh, g2b, b2b, 64, 16384, stream);

  // ---- head ----
  k_last_nhwc<<<(B_*16384)/256, 256, 0, stream>>>(xb2, lw, lb, (float*)d_out);
}

// Round 9
// 2478.384 us; speedup vs baseline: 1.6585x; 1.2895x over previous
//
#include <hip/hip_runtime.h>

#define B_    16
#define NTOK  256
#define D_    512
#define HEADS 16
#define DH    32
#define DEPTH 12
#define KCODE 2048
#define M_    (B_*NTOK)   // 4096 token rows
#define BN_S  512         // BN partial blocks

typedef __attribute__((ext_vector_type(8))) short short8;     // 8 bf16 (4 VGPRs)
typedef __attribute__((ext_vector_type(4))) float float4v;
typedef __attribute__((ext_vector_type(4))) unsigned int uint4v;
typedef __attribute__((ext_vector_type(2))) unsigned int uint2v;
typedef unsigned short ushort;

__device__ __forceinline__ ushort f2b(float f){   // fp32 -> bf16 RNE
  union { float f; unsigned u; } v; v.f = f;
  unsigned r = v.u + 0x7FFFu + ((v.u >> 16) & 1u);
  return (ushort)(r >> 16);
}
__device__ __forceinline__ float b2f(ushort h){
  union { unsigned u; float f; } v; v.u = ((unsigned)h) << 16; return v.f;
}
__device__ __forceinline__ float bits2f(unsigned u){
  union { unsigned u; float f; } v; v.u = u; return v.f;
}

// ---------------- prep kernels ----------------

__global__ void k_tok_init(const float* __restrict__ x, const float* __restrict__ pos,
                           float* __restrict__ tok){
  int i = blockIdx.x*256 + threadIdx.x;
  if (i >= B_*NTOK*D_) return;
  int d = i % D_; int r = i / D_; int t = r % NTOK; int b = r / NTOK;
  tok[i] = x[(b*D_ + d)*NTOK + t] + pos[t*D_ + d];
}

__global__ void k_split(const float* __restrict__ src, ushort* __restrict__ oh,
                        ushort* __restrict__ ol, int n){
  int i = blockIdx.x*256 + threadIdx.x;
  if (i >= n) return;
  float v = src[i];
  ushort h = f2b(v);
  oh[i] = h; ol[i] = f2b(v - b2f(h));
}

// split + transpose: src [L][K][N] f32 -> dst hi/lo [L][N][K] bf16
__global__ void k_split_t(const float* __restrict__ src, ushort* __restrict__ oh,
                          ushort* __restrict__ ol, int L, int K, int N){
  int i = blockIdx.x*256 + threadIdx.x;
  if (i >= L*K*N) return;
  int KN = K*N;
  int l = i / KN; int r = i - l*KN;
  int k = r / N;  int n = r - k*N;
  float v = src[i];
  ushort h = f2b(v);
  size_t o = (size_t)l*KN + (size_t)n*K + k;
  oh[o] = h; ol[o] = f2b(v - b2f(h));
}

// conv weights: [Cout][Cin][3][3] f32 -> W9 [9tap][Cout][Cin] bf16
__global__ void k_w9(const float* __restrict__ w, ushort* __restrict__ W9,
                     int Cin, int Cout){
  int i = blockIdx.x*256 + threadIdx.x;
  if (i >= Cout*Cin*9) return;
  int co = i / (Cin*9); int r = i - co*(Cin*9);
  int ci = r / 9; int tap = r - ci*9;
  W9[((size_t)tap*Cout + co)*Cin + ci] = f2b(w[i]);
}

// upconv weights: [Cin][Cout][2][2] f32 -> Wt4 [tap][Cout][Cin] bf16
__global__ void k_upw(const float* __restrict__ w, ushort* __restrict__ Wt4,
                      int Cin, int Cout){
  int i = blockIdx.x*256 + threadIdx.x;
  if (i >= Cin*Cout*4) return;
  int ci = i / (Cout*4); int r = i - ci*(Cout*4);
  int co = r >> 2; int tap = r & 3;
  Wt4[((size_t)tap*Cout + co)*Cin + ci] = f2b(w[i]);
}

// LayerNorm fused with bf16 hi/lo split
__global__ void k_ln_split(const float* __restrict__ in, ushort* __restrict__ oh,
                           ushort* __restrict__ ol, const float* __restrict__ g,
                           const float* __restrict__ bta){
  int row = blockIdx.x; int t = threadIdx.x;
  const float* xr = in + (size_t)row*D_;
  float x0 = xr[t], x1 = xr[t+256];
  __shared__ float r1[256], r2[256];
  r1[t] = x0+x1; r2[t] = x0*x0 + x1*x1;
  __syncthreads();
  for (int off=128; off>0; off>>=1){
    if (t<off){ r1[t]+=r1[t+off]; r2[t]+=r2[t+off]; }
    __syncthreads();
  }
  float mean = r1[0] * (1.f/D_);
  float var  = r2[0] * (1.f/D_) - mean*mean;
  float inv  = rsqrtf(var + 1e-5f);
  float y0 = (x0-mean)*inv*g[t]     + bta[t];
  float y1 = (x1-mean)*inv*g[t+256] + bta[t+256];
  size_t o = (size_t)row*D_;
  ushort h0 = f2b(y0), h1 = f2b(y1);
  oh[o+t] = h0;     ol[o+t]     = f2b(y0 - b2f(h0));
  oh[o+t+256] = h1; ol[o+t+256] = f2b(y1 - b2f(h1));
}

// ------ split-bf16 MFMA GEMM, 128x128 tile (3-term, fp32-accurate) ------
// C[M][N] = A[M][K] @ B^T (B as [N][K]); 4 waves, each 64x64 quadrant (4x4 accs).
__global__ __launch_bounds__(256,2) void k_gemm_split(
    const ushort* __restrict__ Ah, const ushort* __restrict__ Al,
    const ushort* __restrict__ Bh, const ushort* __restrict__ Bl,
    float* __restrict__ C, const float* __restrict__ bias,
    const float* __restrict__ resid, int M, int N, int K){
  __shared__ ushort Ash[128][36], Asl[128][36], Bsh[128][36], Bsl[128][36];
  const int tid = threadIdx.x;
  const int m_base = blockIdx.x*128, n_base = blockIdx.y*128;
  const int lane = tid & 63, wv = tid >> 6;
  const int quad = lane >> 4, r16 = lane & 15;
  const int m_off = (wv & 1)*64, n_off = (wv >> 1)*64;
  // staging: 512 items/buffer (128 rows x 4 segs); thread does items tid, tid+256
  const int r0 = tid >> 2, sg = tid & 3;          // rows r0 and r0+64
  const size_t a0 = (size_t)(m_base + r0)*K + sg*8;
  const size_t a1 = a0 + (size_t)64*K;
  const size_t b0 = (size_t)(n_base + r0)*K + sg*8;
  const size_t b1 = b0 + (size_t)64*K;
  float4v acc[4][4];
  #pragma unroll
  for (int i = 0; i < 4; ++i)
    #pragma unroll
    for (int j = 0; j < 4; ++j) acc[i][j] = float4v{0.f,0.f,0.f,0.f};
  for (int k0 = 0; k0 < K; k0 += 32){
    *(uint4v*)&Ash[r0   ][sg*8] = *(const uint4v*)(Ah + a0 + k0);
    *(uint4v*)&Ash[r0+64][sg*8] = *(const uint4v*)(Ah + a1 + k0);
    *(uint4v*)&Asl[r0   ][sg*8] = *(const uint4v*)(Al + a0 + k0);
    *(uint4v*)&Asl[r0+64][sg*8] = *(const uint4v*)(Al + a1 + k0);
    *(uint4v*)&Bsh[r0   ][sg*8] = *(const uint4v*)(Bh + b0 + k0);
    *(uint4v*)&Bsh[r0+64][sg*8] = *(const uint4v*)(Bh + b1 + k0);
    *(uint4v*)&Bsl[r0   ][sg*8] = *(const uint4v*)(Bl + b0 + k0);
    *(uint4v*)&Bsl[r0+64][sg*8] = *(const uint4v*)(Bl + b1 + k0);
    __syncthreads();
    short8 ah[4], al[4], bh[4], bl[4];
    #pragma unroll
    for (int i = 0; i < 4; ++i){
      ah[i] = *(const short8*)&Ash[m_off + i*16 + r16][quad*8];
      al[i] = *(const short8*)&Asl[m_off + i*16 + r16][quad*8];
      bh[i] = *(const short8*)&Bsh[n_off + i*16 + r16][quad*8];
      bl[i] = *(const short8*)&Bsl[n_off + i*16 + r16][quad*8];
    }
    #pragma unroll
    for (int i = 0; i < 4; ++i)
      #pragma unroll
      for (int j = 0; j < 4; ++j){
        acc[i][j] = __builtin_amdgcn_mfma_f32_16x16x32_bf16(bh[j], ah[i], acc[i][j], 0,0,0);
        acc[i][j] = __builtin_amdgcn_mfma_f32_16x16x32_bf16(bh[j], al[i], acc[i][j], 0,0,0);
        acc[i][j] = __builtin_amdgcn_mfma_f32_16x16x32_bf16(bl[j], ah[i], acc[i][j], 0,0,0);
      }
    __syncthreads();
  }
  #pragma unroll
  for (int i = 0; i < 4; ++i){
    int m = m_base + m_off + i*16 + r16;
    #pragma unroll
    for (int j = 0; j < 4; ++j){
      int n = n_base + n_off + j*16 + quad*4;
      float4v v = acc[i][j];
      if (bias)  v += *(const float4v*)(bias + n);
      if (resid) v += *(const float4v*)(resid + (size_t)m*N + n);
      *(float4v*)(C + (size_t)m*N + n) = v;
    }
  }
}

// ---------------- attention: one block per (b,h), K/V in LDS ----------------
__global__ __launch_bounds__(256) void k_attn2(const float* __restrict__ qkv,
                                               ushort* __restrict__ oh,
                                               ushort* __restrict__ ol){
  __shared__ float4v ks[NTOK*8];
  __shared__ float4v vs[NTOK*8];
  const int h = blockIdx.x, b = blockIdx.y, t = threadIdx.x;
  const float* base = qkv + (size_t)b*NTOK*1536;
  const int koff = 512 + h*DH, voff = 1024 + h*DH;
  for (int i = t; i < NTOK*8; i += 256){
    int j = i >> 3, d4 = i & 7;
    ks[i] = *(const float4v*)(base + (size_t)j*1536 + koff + d4*4);
    vs[i] = *(const float4v*)(base + (size_t)j*1536 + voff + d4*4);
  }
  float4v q8[8];
  const float* qrow = base + (size_t)t*1536 + h*DH;
  #pragma unroll
  for (int d4 = 0; d4 < 8; ++d4) q8[d4] = *(const float4v*)(qrow + d4*4);
  __syncthreads();
  float4v o8[8];
  #pragma unroll
  for (int d4 = 0; d4 < 8; ++d4) o8[d4] = float4v{0.f,0.f,0.f,0.f};
  float l = 0.f;
  for (int j = 0; j < NTOK; ++j){
    float s = 0.f;
    #pragma unroll
    for (int d4 = 0; d4 < 8; ++d4){
      float4v kk = ks[j*8 + d4];
      s += q8[d4].x*kk.x + q8[d4].y*kk.y + q8[d4].z*kk.z + q8[d4].w*kk.w;
    }
    float e = __expf(s * 0.17677669529663689f);
    l += e;
    #pragma unroll
    for (int d4 = 0; d4 < 8; ++d4){
      float4v vv = vs[j*8 + d4];
      o8[d4].x += e*vv.x; o8[d4].y += e*vv.y; o8[d4].z += e*vv.z; o8[d4].w += e*vv.w;
    }
  }
  float inv = 1.f / l;
  size_t ob = (size_t)(b*NTOK + t)*D_ + h*DH;
  #pragma unroll
  for (int d4 = 0; d4 < 8; ++d4){
    float vals[4] = {o8[d4].x*inv, o8[d4].y*inv, o8[d4].z*inv, o8[d4].w*inv};
    #pragma unroll
    for (int r = 0; r < 4; ++r){
      ushort hh = f2b(vals[r]);
      oh[ob + d4*4 + r] = hh;
      ol[ob + d4*4 + r] = f2b(vals[r] - b2f(hh));
    }
  }
}

// ---------------- VQ ----------------
__global__ void k_cnorm(const float* __restrict__ cb, float* __restrict__ cnorm){
  int k = blockIdx.x, t = threadIdx.x;
  float v1 = cb[(size_t)k*D_ + t];
  float v2 = cb[(size_t)k*D_ + t + 256];
  __shared__ float r[256];
  r[t] = v1*v1 + v2*v2;
  __syncthreads();
  for (int off=128; off>0; off>>=1){
    if (t<off) r[t]+=r[t+off];
    __syncthreads();
  }
  if (t==0) cnorm[k] = r[0];
}

__global__ void k_argmin(const float* __restrict__ d2, const float* __restrict__ cnorm,
                         int* __restrict__ idx){
  int m = blockIdx.x, t = threadIdx.x;
  float best = 3.4e38f; int bk = 0;
  for (int k = t; k < KCODE; k += 256){
    float s = cnorm[k] - 2.f*d2[(size_t)m*KCODE + k];
    if (s < best){ best = s; bk = k; }
  }
  __shared__ float bs[256]; __shared__ int bi[256];
  bs[t]=best; bi[t]=bk;
  __syncthreads();
  for (int off=128; off>0; off>>=1){
    if (t<off){
      if (bs[t+off] < bs[t] || (bs[t+off]==bs[t] && bi[t+off]<bi[t])){
        bs[t]=bs[t+off]; bi[t]=bi[t+off];
      }
    }
    __syncthreads();
  }
  if (t==0) idx[m] = bi[0];
}

// y0 NHWC bf16: y0[b][t][d] = codebook[idx[b,t]][d]
__global__ void k_gather_nhwc(const float* __restrict__ cb, const int* __restrict__ idx,
                              ushort* __restrict__ y0){
  int i = blockIdx.x*256 + threadIdx.x;
  if (i >= B_*NTOK*D_) return;
  int d = i % D_; int r = i / D_; int t = r % NTOK; int b = r / NTOK;
  y0[i] = f2b(cb[(size_t)idx[b*NTOK + t]*D_ + d]);
}

// ---------------- decoder (NHWC bf16) ----------------

// 3x3 conv pad1, patch-staged implicit GEMM + LDS-staged weights.
// 8x8 pixel tile -> 10x10 patch; weights [9][64co][32ch] cooperatively staged.
// grid ((H/8)*(W/8), Cout/64, B_).
__global__ __launch_bounds__(256) void k_conv_nhwc(
    const ushort* __restrict__ X, const ushort* __restrict__ W9,
    float* __restrict__ Y, int Cin, int Cout, int H, int W){
  __shared__ ushort Xs[128][36];      // 10x10 patch rows x 32ch (100 rows used)
  __shared__ ushort Ws[576][36];      // 9 taps x 64 co x 32 ch
  const int HW = H*W;
  const int tid = threadIdx.x;
  const int b = blockIdx.z;
  const int tiles_w = W >> 3;
  const int th0 = (blockIdx.x / tiles_w) * 8;
  const int tw0 = (blockIdx.x - (blockIdx.x / tiles_w)*tiles_w) * 8;
  const int n_base = blockIdx.y*64;
  const int lane = tid & 63, wv = tid >> 6;
  const int quad = lane >> 4, r16 = lane & 15;
  const int m_off = (wv & 1)*32, n_off = (wv >> 1)*32;
  const ushort* Xb = X + (size_t)b*HW*Cin;
  // X staging precompute: 400 items (100 patch rows x 4 ch-segments), 2/thread
  const ushort* sptr[2]; int srw[2], ssg[2]; bool sok[2];
  #pragma unroll
  for (int e = 0; e < 2; ++e){
    int item = tid + e*256;
    int row = (item >> 2) & 127;
    int seg = item & 3;
    int ph = row / 10, pw = row - ph*10;
    int gh = th0 + ph - 1, gw = tw0 + pw - 1;
    bool ok = (item < 400) && gh >= 0 && gh < H && gw >= 0 && gw < W;
    int pidx = ok ? (gh*W + gw) : 0;
    srw[e] = row; ssg[e] = seg; sok[e] = ok;
    sptr[e] = Xb + ((size_t)pidx*Cin + seg*8);
  }
  // W staging precompute: 2304 items (576 rows x 4 segs), 9/thread
  const ushort* wptr[9]; int wrw[9], wsg[9];
  #pragma unroll
  for (int e = 0; e < 9; ++e){
    int item = tid + e*256;
    int row = item >> 2;                 // 0..575
    int seg = item & 3;
    int tap = row >> 6, co = row & 63;
    wrw[e] = row; wsg[e] = seg;
    wptr[e] = W9 + ((size_t)tap*Cout + n_base + co)*Cin + seg*8;
  }
  const uint4v zz = {};
  float4v a00={}, a01={}, a10={}, a11={};
  const int mA = m_off + r16, mB = mA + 16;
  const int rA0 = ((mA>>3))*10 + (mA&7);    // patch row for tap (0,0)
  const int rB0 = ((mB>>3))*10 + (mB&7);
  for (int k0 = 0; k0 < Cin; k0 += 32){
    if (k0) __syncthreads();
    #pragma unroll
    for (int e = 0; e < 2; ++e){
      uint4v v = sok[e] ? *(const uint4v*)(sptr[e] + k0) : zz;
      *(uint4v*)&Xs[srw[e]][ssg[e]*8] = v;
    }
    #pragma unroll
    for (int e = 0; e < 9; ++e)
      *(uint4v*)&Ws[wrw[e]][wsg[e]*8] = *(const uint4v*)(wptr[e] + k0);
    __syncthreads();
    #pragma unroll
    for (int tap = 0; tap < 9; ++tap){
      const int kh = tap/3, kw = tap - (tap/3)*3;
      short8 wf0 = *(const short8*)&Ws[tap*64 + n_off      + r16][quad*8];
      short8 wf1 = *(const short8*)&Ws[tap*64 + n_off + 16 + r16][quad*8];
      short8 xf0 = *(const short8*)&Xs[rA0 + kh*10 + kw][quad*8];
      short8 xf1 = *(const short8*)&Xs[rB0 + kh*10 + kw][quad*8];
      a00 = __builtin_amdgcn_mfma_f32_16x16x32_bf16(wf0, xf0, a00, 0,0,0);
      a01 = __builtin_amdgcn_mfma_f32_16x16x32_bf16(wf0, xf1, a01, 0,0,0);
      a10 = __builtin_amdgcn_mfma_f32_16x16x32_bf16(wf1, xf0, a10, 0,0,0);
      a11 = __builtin_amdgcn_mfma_f32_16x16x32_bf16(wf1, xf1, a11, 0,0,0);
    }
  }
  float* Yb = Y + (size_t)b*HW*Cout;
  int pA = (th0 + (mA>>3))*W + tw0 + (mA&7);
  int pB = (th0 + (mB>>3))*W + tw0 + (mB&7);
  int co0 = n_base + n_off + quad*4, co1 = co0 + 16;
  *(float4v*)(Yb + (size_t)pA*Cout + co0) = a00;
  *(float4v*)(Yb + (size_t)pB*Cout + co0) = a01;
  *(float4v*)(Yb + (size_t)pA*Cout + co1) = a10;
  *(float4v*)(Yb + (size_t)pB*Cout + co1) = a11;
}

// ConvTranspose2d k=2 s=2: X staged once per K-chunk, 4 weight taps share it.
__global__ __launch_bounds__(256) void k_upconv_nhwc(
    const ushort* __restrict__ X, const ushort* __restrict__ Wt4,
    const float* __restrict__ bias, ushort* __restrict__ CC,
    int Cin, int Cout, int Hi, int Wi, int Ctot){
  __shared__ ushort Xs[64][40], Ws[4][64][40];
  const int HWi = Hi*Wi;
  const int tid = threadIdx.x;
  const int b = blockIdx.z;
  const int m_base = blockIdx.x*64;
  const int n_base = blockIdx.y*64;
  const int lane = tid & 63, wv = tid >> 6;
  const int quad = lane >> 4, r16 = lane & 15;
  const int m_off = (wv & 1)*32, n_off = (wv >> 1)*32;
  const int srow = tid & 63, skq = tid >> 6;
  const ushort* xrow = X + ((size_t)b*HWi + m_base + srow)*Cin + skq*8;
  const ushort* w0 = Wt4 + ((size_t)0*Cout + n_base + srow)*Cin + skq*8;
  const ushort* w1 = Wt4 + ((size_t)1*Cout + n_base + srow)*Cin + skq*8;
  const ushort* w2 = Wt4 + ((size_t)2*Cout + n_base + srow)*Cin + skq*8;
  const ushort* w3 = Wt4 + ((size_t)3*Cout + n_base + srow)*Cin + skq*8;
  float4v acc[4][4];
  #pragma unroll
  for (int t = 0; t < 4; ++t)
    #pragma unroll
    for (int q = 0; q < 4; ++q) acc[t][q] = float4v{0.f,0.f,0.f,0.f};
  for (int k0 = 0; k0 < Cin; k0 += 32){
    *(uint4v*)&Xs[srow][skq*8]    = *(const uint4v*)(xrow + k0);
    *(uint4v*)&Ws[0][srow][skq*8] = *(const uint4v*)(w0 + k0);
    *(uint4v*)&Ws[1][srow][skq*8] = *(const uint4v*)(w1 + k0);
    *(uint4v*)&Ws[2][srow][skq*8] = *(const uint4v*)(w2 + k0);
    *(uint4v*)&Ws[3][srow][skq*8] = *(const uint4v*)(w3 + k0);
    __syncthreads();
    short8 xf0 = *(const short8*)&Xs[m_off      + r16][quad*8];
    short8 xf1 = *(const short8*)&Xs[m_off + 16 + r16][quad*8];
    #pragma unroll
    for (int t = 0; t < 4; ++t){
      short8 wf0 = *(const short8*)&Ws[t][n_off      + r16][quad*8];
      short8 wf1 = *(const short8*)&Ws[t][n_off + 16 + r16][quad*8];
      acc[t][0] = __builtin_amdgcn_mfma_f32_16x16x32_bf16(wf0, xf0, acc[t][0], 0,0,0);
      acc[t][1] = __builtin_amdgcn_mfma_f32_16x16x32_bf16(wf0, xf1, acc[t][1], 0,0,0);
      acc[t][2] = __builtin_amdgcn_mfma_f32_16x16x32_bf16(wf1, xf0, acc[t][2], 0,0,0);
      acc[t][3] = __builtin_amdgcn_mfma_f32_16x16x32_bf16(wf1, xf1, acc[t][3], 0,0,0);
    }
    __syncthreads();
  }
  const int Wo = 2*Wi, HWo = 4*HWi;
  int co0 = n_base + n_off + quad*4, co1 = co0 + 16;
  float4v bv0 = *(const float4v*)(bias + co0);
  float4v bv1 = *(const float4v*)(bias + co1);
  int px0 = m_base + m_off + r16, px1 = px0 + 16;
  #pragma unroll
  for (int j = 0; j < 2; ++j){
    int p = j ? px1 : px0;
    int r = p / Wi, c = p - r*Wi;
    #pragma unroll
    for (int t = 0; t < 4; ++t){
      int opix = (2*r + (t>>1))*Wo + 2*c + (t&1);
      ushort* o = CC + ((size_t)b*HWo + opix)*Ctot;
      float4v vA = acc[t][0 + j] + bv0;
      float4v vB = acc[t][2 + j] + bv1;
      uint2v pA, pB;
      pA.x = (unsigned)f2b(vA.x) | ((unsigned)f2b(vA.y) << 16);
      pA.y = (unsigned)f2b(vA.z) | ((unsigned)f2b(vA.w) << 16);
      pB.x = (unsigned)f2b(vB.x) | ((unsigned)f2b(vB.y) << 16);
      pB.y = (unsigned)f2b(vB.z) | ((unsigned)f2b(vB.w) << 16);
      *(uint2v*)(o + co0) = pA;
      *(uint2v*)(o + co1) = pB;
    }
  }
}

// NCHW fp32 skip feature -> NHWC bf16 concat channels [Coff, Coff+Cf)
__global__ void k_feat2cc(const float* __restrict__ feat, ushort* __restrict__ cc,
                          int Cf, int Coff, int Ctot, int HW){
  __shared__ ushort t[32][33];
  int pb = blockIdx.x*32, cbs = blockIdx.y*32, b = blockIdx.z;
  int tx = threadIdx.x, ty = threadIdx.y;
  #pragma unroll
  for (int i = 0; i < 4; ++i){
    int c = cbs + ty + i*8;
    t[ty + i*8][tx] = f2b(feat[((size_t)(b*Cf) + c)*HW + pb + tx]);
  }
  __syncthreads();
  #pragma unroll
  for (int i = 0; i < 4; ++i){
    int p = pb + ty + i*8;
    cc[((size_t)b*HW + p)*Ctot + Coff + cbs + tx] = t[tx][ty + i*8];
  }
}

// BN stats phase 1: BN_S blocks, float4 channel-quads, LDS cross-group reduce.
__global__ __launch_bounds__(256) void k_bnstats_nhwc(
    const float* __restrict__ x, float* __restrict__ part, int C, int HW){
  const int s = blockIdx.x, tid = threadIdx.x;
  const int R = B_*HW;
  const int chunk = R / BN_S;
  const int L = C >> 2;
  const int G = 256 / L;
  const int c4 = tid % L, g = tid / L;
  float4v a = {}, q = {};
  const float* xb = x + (size_t)(s*chunk)*C + 4*c4;
  for (int r = g; r < chunk; r += G){
    float4v v = *(const float4v*)(xb + (size_t)r*C);
    a += v; q += v*v;
  }
  __shared__ float4v h1[256], h2[256];
  h1[tid] = a; h2[tid] = q;
  __syncthreads();
  if (tid < L){
    float4v ra = h1[tid], rq = h2[tid];
    for (int gg = 1; gg < G; ++gg){ ra += h1[tid + gg*L]; rq += h2[tid + gg*L]; }
    int c0 = 4*c4;
    part[(size_t)(c0+0)*BN_S + s] = ra.x;
    part[(size_t)(c0+1)*BN_S + s] = ra.y;
    part[(size_t)(c0+2)*BN_S + s] = ra.z;
    part[(size_t)(c0+3)*BN_S + s] = ra.w;
    part[(size_t)(C+c0+0)*BN_S + s] = rq.x;
    part[(size_t)(C+c0+1)*BN_S + s] = rq.y;
    part[(size_t)(C+c0+2)*BN_S + s] = rq.z;
    part[(size_t)(C+c0+3)*BN_S + s] = rq.w;
  }
}

// BN finalize: one block per channel reduces BN_S partials -> scale/shift
__global__ void k_bnfinal(const float* __restrict__ part, const float* __restrict__ g,
                          const float* __restrict__ bb, float* __restrict__ scale,
                          float* __restrict__ shift, int C, int cnt){
  int c = blockIdx.x, t = threadIdx.x;  // 256 threads
  __shared__ float r1[256], r2[256];
  r1[t] = part[(size_t)c*BN_S + t]       + part[(size_t)c*BN_S + t + 256];
  r2[t] = part[(size_t)(C + c)*BN_S + t] + part[(size_t)(C + c)*BN_S + t + 256];
  __syncthreads();
  for (int off = 128; off > 0; off >>= 1){
    if (t < off){ r1[t] += r1[t+off]; r2[t] += r2[t+off]; }
    __syncthreads();
  }
  if (t == 0){
    float m = r1[0]/cnt;
    float v = r2[0]/cnt - m*m;
    float sc = g[c]*rsqrtf(v + 1e-5f);
    scale[c] = sc;
    shift[c] = bb[c] - m*sc;
  }
}

// BN apply + ReLU, fp32 NHWC -> bf16 NHWC
__global__ void k_bnapply_nhwc(const float* __restrict__ x, ushort* __restrict__ y,
                               const float* __restrict__ scale,
                               const float* __restrict__ shift, int C, int n4){
  int i = blockIdx.x*256 + threadIdx.x;
  if (i >= n4) return;
  float4v v = *(const float4v*)(x + (size_t)4*i);
  int c0 = (4*i) % C;
  float4v sc = *(const float4v*)(scale + c0);
  float4v sh = *(const float4v*)(shift + c0);
  float r0 = fmaxf(v.x*sc.x + sh.x, 0.f);
  float r1 = fmaxf(v.y*sc.y + sh.y, 0.f);
  float r2 = fmaxf(v.z*sc.z + sh.z, 0.f);
  float r3 = fmaxf(v.w*sc.w + sh.w, 0.f);
  uint2v pk;
  pk.x = (unsigned)f2b(r0) | ((unsigned)f2b(r1) << 16);
  pk.y = (unsigned)f2b(r2) | ((unsigned)f2b(r3) << 16);
  *(uint2v*)(y + (size_t)4*i) = pk;
}

// final 1x1 conv (64ch NHWC bf16 -> 1) + sigmoid
__global__ void k_last_nhwc(const ushort* __restrict__ x, const float* __restrict__ lw,
                            const float* __restrict__ lb, float* __restrict__ out){
  __shared__ float wsm[64];
  int tid = threadIdx.x;
  if (tid < 64) wsm[tid] = lw[tid];
  __syncthreads();
  int i = blockIdx.x*256 + tid;
  const uint4v* xr = (const uint4v*)(x + (size_t)i*64);
  float acc = lb[0];
  #pragma unroll
  for (int q = 0; q < 8; ++q){
    uint4v u = xr[q];
    unsigned uu[4] = {u.x, u.y, u.z, u.w};
    #pragma unroll
    for (int k = 0; k < 4; ++k){
      acc += bits2f(uu[k] << 16)          * wsm[q*8 + 2*k];
      acc += bits2f(uu[k] & 0xffff0000u)  * wsm[q*8 + 2*k + 1];
    }
  }
  out[i] = 1.f/(1.f + __expf(-acc));
}

// ---------------- host ----------------
#define MBx 1048576ull

static inline void run_conv(const ushort* in, const float* w, ushort* W9,
                            float* out, int Cin, int Cout, int H, int W,
                            hipStream_t stream){
  int total = Cout*Cin*9;
  k_w9<<<(total+255)/256, 256, 0, stream>>>(w, W9, Cin, Cout);
  k_conv_nhwc<<<dim3((H>>3)*(W>>3), Cout/64, B_), 256, 0, stream>>>(in, W9, out, Cin, Cout, H, W);
}

static inline void run_bn(const float* x, ushort* y, float* part, float* scale, float* shift,
                          const float* g, const float* bb, int C, int HW, hipStream_t stream){
  k_bnstats_nhwc<<<BN_S, 256, 0, stream>>>(x, part, C, HW);
  k_bnfinal<<<C, 256, 0, stream>>>(part, g, bb, scale, shift, C, B_*HW);
  int n4 = B_*HW*C/4;
  k_bnapply_nhwc<<<(n4+255)/256, 256, 0, stream>>>(x, y, scale, shift, C, n4);
}

extern "C" void kernel_launch(void* const* d_in, const int* in_sizes, int n_in,
                              void* d_out, int out_size, void* d_ws, size_t ws_size,
                              hipStream_t stream){
  const float* x     = (const float*)d_in[0];
  const float* feat0 = (const float*)d_in[1];
  const float* feat1 = (const float*)d_in[2];
  const float* feat2 = (const float*)d_in[3];
  const float* pos   = (const float*)d_in[4];
  const float* cb    = (const float*)d_in[5];
  const float* ln_g  = (const float*)d_in[6];
  const float* ln_b  = (const float*)d_in[7];
  const float* wqkv  = (const float*)d_in[8];
  const float* wo    = (const float*)d_in[9];
  const float* bo    = (const float*)d_in[10];
  const float* up_w0 = (const float*)d_in[11];
  const float* up_b0 = (const float*)d_in[12];
  const float* cw0a  = (const float*)d_in[13];
  const float* g0a   = (const float*)d_in[14];
  const float* b0a   = (const float*)d_in[15];
  const float* cw0b  = (const float*)d_in[16];
  const float* g0b   = (const float*)d_in[17];
  const float* b0b   = (const float*)d_in[18];
  const float* up_w1 = (const float*)d_in[19];
  const float* up_b1 = (const float*)d_in[20];
  const float* cw1a  = (const float*)d_in[21];
  const float* g1a   = (const float*)d_in[22];
  const float* b1a   = (const float*)d_in[23];
  const float* cw1b  = (const float*)d_in[24];
  const float* g1b   = (const float*)d_in[25];
  const float* b1b   = (const float*)d_in[26];
  const float* up_w2 = (const float*)d_in[27];
  const float* up_b2 = (const float*)d_in[28];
  const float* cw2a  = (const float*)d_in[29];
  const float* g2a   = (const float*)d_in[30];
  const float* b2a   = (const float*)d_in[31];
  const float* cw2b  = (const float*)d_in[32];
  const float* g2b   = (const float*)d_in[33];
  const float* b2b   = (const float*)d_in[34];
  const float* lw    = (const float*)d_in[35];
  const float* lb    = (const float*)d_in[36];

  char* ws = (char*)d_ws;
  // encoder/VQ scratch (region 0..134MB)
  float*  tok     = (float*) (ws);
  ushort* xn_hi   = (ushort*)(ws +  8388608ull);
  ushort* xn_lo   = (ushort*)(ws + 12582912ull);
  float*  qkv     = (float*) (ws + 16777216ull);
  ushort* at_hi   = (ushort*)(ws + 41943040ull);
  ushort* at_lo   = (ushort*)(ws + 46137344ull);
  ushort* tok_hi  = (ushort*)(ws + 50331648ull);
  ushort* tok_lo  = (ushort*)(ws + 54525952ull);
  ushort* Wq_hi   = (ushort*)(ws + 58720256ull);
  ushort* Wq_lo   = (ushort*)(ws + 77594624ull);
  ushort* Wo_hi   = (ushort*)(ws + 96468992ull);
  ushort* Wo_lo   = (ushort*)(ws + 102760448ull);
  ushort* cb_hi   = (ushort*)(ws + 109051904ull);
  ushort* cb_lo   = (ushort*)(ws + 111149056ull);
  float*  cnorm   = (float*) (ws + 113246208ull);
  int*    idx     = (int*)   (ws + 113254400ull);
  float*  d2      = (float*) (ws + 58720256ull);   // overlaps Wq (dead at VQ time)
  // tail: weights + bn scratch + y0
  ushort* W9   = (ushort*)(ws + 134*MBx);          // 2.25 MB max
  float* bnsc  = (float*) (ws + 136*MBx + 524288); // 1 KB
  float* bnsh  = (float*) (ws + 136*MBx + 528384); // 1 KB
  ushort* Wt4  = (ushort*)(ws + 137*MBx);          // 1 MB max
  float* bnp   = (float*) (ws + 138*MBx);          // 1 MB max
  ushort* y0   = (ushort*)(ws + 139*MBx);
  // decoder ping-pong
  ushort* cc0 = (ushort*)(ws + 146*MBx);
  float*  va0 = (float*) (ws + 163*MBx);
  ushort* xa0 = (ushort*)(ws + 180*MBx);
  float*  vb0 = (float*) (ws + 146*MBx);
  ushort* xb0 = (ushort*)(ws + 189*MBx);
  ushort* cc1 = (ushort*)(ws + 0*MBx);
  float*  va1 = (float*) (ws + 34*MBx);
  ushort* xa1 = (ushort*)(ws + 68*MBx);
  float*  vb1 = (float*) (ws + 85*MBx);
  ushort* xb1 = (ushort*)(ws + 146*MBx);
  ushort* cc2 = (ushort*)(ws + 0*MBx);
  float*  va2 = (float*) (ws + 67*MBx);
  ushort* xa2 = (ushort*)(ws + 146*MBx);
  float*  vb2 = (float*) (ws + 0*MBx);
  ushort* xb2 = (ushort*)(ws + 67*MBx);

  // ---- weight prep ----
  k_split_t<<<(DEPTH*D_*1536+255)/256, 256, 0, stream>>>(wqkv, Wq_hi, Wq_lo, DEPTH, D_, 1536);
  k_split_t<<<(DEPTH*D_*D_+255)/256, 256, 0, stream>>>(wo, Wo_hi, Wo_lo, DEPTH, D_, D_);
  k_split<<<(KCODE*D_+255)/256, 256, 0, stream>>>(cb, cb_hi, cb_lo, KCODE*D_);
  k_cnorm<<<KCODE, 256, 0, stream>>>(cb, cnorm);

  // ---- encoder ----
  k_tok_init<<<(B_*NTOK*D_)/256, 256, 0, stream>>>(x, pos, tok);
  for (int l = 0; l < DEPTH; ++l){
    k_ln_split<<<M_, 256, 0, stream>>>(tok, xn_hi, xn_lo, ln_g + l*D_, ln_b + l*D_);
    k_gemm_split<<<dim3(M_/128, 1536/128), 256, 0, stream>>>(
        xn_hi, xn_lo, Wq_hi + (size_t)l*1536*D_, Wq_lo + (size_t)l*1536*D_,
        qkv, nullptr, nullptr, M_, 1536, D_);
    k_attn2<<<dim3(HEADS, B_), 256, 0, stream>>>(qkv, at_hi, at_lo);
    k_gemm_split<<<dim3(M_/128, D_/128), 256, 0, stream>>>(
        at_hi, at_lo, Wo_hi + (size_t)l*D_*D_, Wo_lo + (size_t)l*D_*D_,
        tok, bo + l*D_, tok, M_, D_, D_);
  }

  // ---- VQ ----
  k_split<<<(M_*D_+255)/256, 256, 0, stream>>>(tok, tok_hi, tok_lo, M_*D_);
  k_gemm_split<<<dim3(M_/128, KCODE/128), 256, 0, stream>>>(
      tok_hi, tok_lo, cb_hi, cb_lo, d2, nullptr, nullptr, M_, KCODE, D_);
  k_argmin<<<M_, 256, 0, stream>>>(d2, cnorm, idx);
  k_gather_nhwc<<<(B_*NTOK*D_)/256, 256, 0, stream>>>(cb, idx, y0);

  // ---- decoder stage 0: 16x16 -> 32x32, Ctot=512 ----
  k_upw<<<(512*256*4+255)/256, 256, 0, stream>>>(up_w0, Wt4, 512, 256);
  k_upconv_nhwc<<<dim3(256/64, 256/64, B_), 256, 0, stream>>>(y0, Wt4, up_b0, cc0, 512, 256, 16, 16, 512);
  k_feat2cc<<<dim3(1024/32, 256/32, B_), dim3(32,8), 0, stream>>>(feat2, cc0, 256, 256, 512, 1024);
  run_conv(cc0, cw0a, W9, va0, 512, 256, 32, 32, stream);
  run_bn(va0, xa0, bnp, bnsc, bnsh, g0a, b0a, 256, 1024, stream);
  run_conv(xa0, cw0b, W9, vb0, 256, 256, 32, 32, stream);
  run_bn(vb0, xb0, bnp, bnsc, bnsh, g0b, b0b, 256, 1024, stream);

  // ---- decoder stage 1: 32x32 -> 64x64, Ctot=256 ----
  k_upw<<<(256*128*4+255)/256, 256, 0, stream>>>(up_w1, Wt4, 256, 128);
  k_upconv_nhwc<<<dim3(1024/64, 128/64, B_), 256, 0, stream>>>(xb0, Wt4, up_b1, cc1, 256, 128, 32, 32, 256);
  k_feat2cc<<<dim3(4096/32, 128/32, B_), dim3(32,8), 0, stream>>>(feat1, cc1, 128, 128, 256, 4096);
  run_conv(cc1, cw1a, W9, va1, 256, 128, 64, 64, stream);
  run_bn(va1, xa1, bnp, bnsc, bnsh, g1a, b1a, 128, 4096, stream);
  run_conv(xa1, cw1b, W9, vb1, 128, 128, 64, 64, stream);
  run_bn(vb1, xb1, bnp, bnsc, bnsh, g1b, b1b, 128, 4096, stream);

  // ---- decoder stage 2: 64x64 -> 128x128, Ctot=128 ----
  k_upw<<<(128*64*4+255)/256, 256, 0, stream>>>(up_w2, Wt4, 128, 64);
  k_upconv_nhwc<<<dim3(4096/64, 64/64, B_), 256, 0, stream>>>(xb1, Wt4, up_b2, cc2, 128, 64, 64, 64, 128);
  k_feat2cc<<<dim3(16384/32, 64/32, B_), dim3(32,8), 0, stream>>>(feat0, cc2, 64, 64, 128, 16384);
  run_conv(cc2, cw2a, W9, va2, 128, 64, 128, 128, stream);
  run_bn(va2, xa2, bnp, bnsc, bnsh, g2a, b2a, 64, 16384, stream);
  run_conv(xa2, cw2b, W9, vb2, 64, 64, 128, 128, stream);
  run_bn(vb2, xb2, bnp, bnsc, bnsh, g2b, b2b, 64, 16384, stream);

  // ---- head ----
  k_last_nhwc<<<(B_*16384)/256, 256, 0, stream>>>(xb2, lw, lb, (float*)d_out);
}